// Round 7
// baseline (240.210 us; speedup 1.0000x reference)
//
#include <hip/hip_runtime.h>
#include <math.h>

// ---------------------------------------------------------------------------
// QuantumCritic R10.
//   psi = W r (W = U*D fixed 256x256 complex bf16, r real product vector)
//   P = |psi|^2 ; ex@w3 = P @ G (G = S^T w3 fixed bf16)
// R10 changes vs R9 (post-mortem: qgemm = serial sum of MFMA 6.1K + DS 10.3K
// + VALU 2.4K cyc/iter at 2 waves/SIMD; phase1 runs two 16-deep ds_read->MFMA
// chains SEQUENTIALLY with P-writes fencing between -> ds_read ~120cy latency
// exposed per step. Occupancy is register-capped (W-frags) — intra-wave ILP
// is the only overlap lever):
//   - qgemm phase1: subtile0/subtile1 chains MERGED into one loop, 4
//     independent accumulators (a00,a01,a10,a11). Two independent dep-chains
//     hide ds_read latency under the other subtile's MFMAs. P-writes for both
//     subtiles after the loop. FP order per-acc bit-identical to R6/R9.
//     +32 live AGPRs; launch_bounds(512,2) unchanged (still <=256 regs/wave).
//   - everything else byte-identical to R9 (enc_mfma 32-row/4-waves, qgemm
//     otherwise R6-validated, prep unchanged).
// ---------------------------------------------------------------------------

typedef __attribute__((ext_vector_type(8))) short bfrag_t;   // 8 bf16 = 4 VGPR
typedef __attribute__((ext_vector_type(16))) float accv_t;   // 32x32 MFMA acc

__device__ __forceinline__ unsigned short f2bf(float x) {
  unsigned u = __float_as_uint(x);
  u += 0x7FFFu + ((u >> 16) & 1u);      // RNE
  return (unsigned short)(u >> 16);
}
__device__ __forceinline__ float bf2f(unsigned short h) {
  return __uint_as_float(((unsigned)h) << 16);
}
__device__ __forceinline__ unsigned pack2(float a, float b) {
  return (unsigned)f2bf(a) | ((unsigned)f2bf(b) << 16);
}

struct C2 { float r, i; };
__device__ __forceinline__ C2 cmul(C2 a, C2 b){ return C2{a.r*b.r - a.i*b.i, a.r*b.i + a.i*b.r}; }
__device__ __forceinline__ C2 cadd(C2 a, C2 b){ return C2{a.r+b.r, a.i+b.i}; }

#define APPLY2(A,Bx)                                                        \
  { float ar=re[A], ai=im[A], br=re[Bx], bi=im[Bx];                         \
    re[A]  = u00r*ar - u00i*ai + u01r*br - u01i*bi;                         \
    im[A]  = u00r*ai + u00i*ar + u01r*bi + u01i*br;                         \
    re[Bx] = u10r*ar - u10i*ai + u11r*br - u11i*bi;                         \
    im[Bx] = u10r*ai + u10i*ar + u11r*bi + u11i*br; }

__global__ __launch_bounds__(256)
void prep_weights(const float* __restrict__ qrxa, const float* __restrict__ qrya,
                  const float* __restrict__ qrza,
                  const float* __restrict__ qrxb, const float* __restrict__ qryb,
                  const float* __restrict__ qrzb,
                  const float* __restrict__ w1a, const float* __restrict__ w1b,
                  const float* __restrict__ w2a, const float* __restrict__ w2b,
                  const float* __restrict__ w3a, const float* __restrict__ w3b,
                  unsigned short* __restrict__ Bm, unsigned short* __restrict__ Gm,
                  unsigned short* __restrict__ w1p, unsigned short* __restrict__ w2p) {
  int blk = blockIdx.x;
  int tid = threadIdx.x;
  if (blk < 128) {
    // ---- prep_W: circuit on 256 basis columns ----
    __shared__ float sg[192];
    int c = blk >> 6;
    if (tid < 24) {
      const float* qx = c ? qrxb : qrxa;
      const float* qy = c ? qryb : qrya;
      const float* qz = c ? qrzb : qrza;
      int g = tid;
      float tx = 0.5f*qx[g], ty = 0.5f*qy[g], tz = 0.5f*qz[g];
      float cx = cosf(tx), sx = sinf(tx);
      float cy = cosf(ty), sy = sinf(ty);
      float cz = cosf(tz), sz = sinf(tz);
      C2 rx00{cx,0.f}, rx01{0.f,-sx}, rx10{0.f,-sx}, rx11{cx,0.f};
      C2 m00 = cadd(cmul(C2{cy,0.f},rx00), cmul(C2{-sy,0.f},rx10));
      C2 m01 = cadd(cmul(C2{cy,0.f},rx01), cmul(C2{-sy,0.f},rx11));
      C2 m10 = cadd(cmul(C2{sy,0.f},rx00), cmul(C2{cy,0.f},rx10));
      C2 m11 = cadd(cmul(C2{sy,0.f},rx01), cmul(C2{cy,0.f},rx11));
      C2 e0{cz,-sz}, e1{cz,sz};
      C2 u00 = cmul(e0,m00), u01 = cmul(e0,m01), u10 = cmul(e1,m10), u11 = cmul(e1,m11);
      float* o = sg + g*8;
      o[0]=u00.r; o[1]=u00.i; o[2]=u01.r; o[3]=u01.i;
      o[4]=u10.r; o[5]=u10.i; o[6]=u11.r; o[7]=u11.i;
    }
    __syncthreads();
    int lane = tid & 63;
    int wid = blk*4 + (tid >> 6);
    int bcol = wid & 255;
    int p = __popc(bcol) & 3;
    float phr = (p==0) ? 1.f : ((p==2) ? -1.f : 0.f);
    float phi = (p==1) ? -1.f : ((p==3) ? 1.f : 0.f);
    float re[4], im[4];
    #pragma unroll
    for (int j = 0; j < 4; ++j) {
      int idx = 4*lane + j;
      re[j] = (idx==bcol) ? phr : 0.f;
      im[j] = (idx==bcol) ? phi : 0.f;
    }
    #pragma unroll
    for (int l = 0; l < 3; ++l) {
      #pragma unroll
      for (int q = 0; q < 8; ++q) {
        const float* u = &sg[(size_t)(l*8 + q)*8];
        float u00r=u[0],u00i=u[1],u01r=u[2],u01i=u[3];
        float u10r=u[4],u10i=u[5],u11r=u[6],u11i=u[7];
        if (q < 6) {
          int m = 5-q, mask = 1<<m;
          bool s1 = ((lane >> m) & 1) != 0;
          float udr = s1?u11r:u00r, udi = s1?u11i:u00i;
          float uor = s1?u10r:u01r, uoi = s1?u10i:u01i;
          #pragma unroll
          for (int j = 0; j < 4; ++j) {
            float pr = __shfl_xor(re[j], mask);
            float pi = __shfl_xor(im[j], mask);
            float nr = udr*re[j] - udi*im[j] + uor*pr - uoi*pi;
            float ni = udr*im[j] + udi*re[j] + uor*pi + uoi*pr;
            re[j]=nr; im[j]=ni;
          }
        } else if (q == 6) { APPLY2(0,2); APPLY2(1,3); }
        else               { APPLY2(0,1); APPLY2(2,3); }
      }
      #pragma unroll
      for (int cq = 0; cq <= 4; ++cq) {
        int tmask = 1 << (4-cq);
        bool pred = ((lane >> (5-cq)) & 1) != 0;
        #pragma unroll
        for (int j = 0; j < 4; ++j) {
          float sr = __shfl_xor(re[j], tmask);
          float si = __shfl_xor(im[j], tmask);
          re[j] = pred ? sr : re[j];
          im[j] = pred ? si : im[j];
        }
      }
      { bool pred = (lane & 1) != 0;
        float t0, t1;
        t0 = pred?re[2]:re[0]; t1 = pred?re[0]:re[2]; re[0]=t0; re[2]=t1;
        t0 = pred?im[2]:im[0]; t1 = pred?im[0]:im[2]; im[0]=t0; im[2]=t1;
        t0 = pred?re[3]:re[1]; t1 = pred?re[1]:re[3]; re[1]=t0; re[3]=t1;
        t0 = pred?im[3]:im[1]; t1 = pred?im[1]:im[3]; im[1]=t0; im[3]=t1; }
      { float t;
        t=re[2]; re[2]=re[3]; re[3]=t;
        t=im[2]; im[2]=im[3]; im[3]=t; }
      { re[1]=__shfl_xor(re[1],32); im[1]=__shfl_xor(im[1],32);
        re[3]=__shfl_xor(re[3],32); im[3]=__shfl_xor(im[3],32); }
    }
    #pragma unroll
    for (int j = 0; j < 4; ++j) {
      int i = 4*lane + j;
      Bm[(size_t)(c*512 + i)*256 + bcol]       = f2bf(re[j]);
      Bm[(size_t)(c*512 + 256 + i)*256 + bcol] = f2bf(im[j]);
    }
  } else if (blk < 192) {
    // ---- w1pack ----
    int slot = (blk-128)*256 + tid;
    int n = slot & 255, h5 = (slot>>8)&1, ks = (slot>>9)&7, p = (slot>>12)&1, c = slot>>13;
    const float* w1c = c ? w1b : w1a;
    #pragma unroll
    for (int j = 0; j < 8; ++j) {
      float v = w1c[(size_t)(ks*16 + h5*8 + j)*256 + n];
      unsigned short hi = f2bf(v);
      w1p[(size_t)slot*8 + j] = p ? f2bf(v - bf2f(hi)) : hi;
    }
  } else if (blk < 200) {
    // ---- w2pack ----
    int slot = (blk-192)*256 + tid;
    int combo = slot >> 4, part = slot & 15;
    int h5 = combo&1, k16 = (combo>>1)&15, p = (combo>>5)&1, c = (combo>>6)&1;
    const float* w2c = c ? w2b : w2a;
    #pragma unroll
    for (int jj = 0; jj < 16; ++jj) {
      int idx = part*16 + jj;
      int il = idx >> 3, j = idx & 7;
      int n = k16*16 + h5*8 + j;
      float v = (il < 8) ? w2c[(size_t)n*8 + il] : 0.f;
      unsigned short hi = f2bf(v);
      w2p[(size_t)combo*256 + idx] = p ? f2bf(v - bf2f(hi)) : hi;
    }
  } else {
    // ---- Gmat in qgemm frag order:
    // Gm[((c*8+w)*16+ks)*512 + lane*8 + j] = G[n=32w+(lane&31)][i=ks*16+(lane>>5)*8+j]
    int idx = (blk-200)*256 + tid;          // [0, 131072)
    int c = idx >> 16, w = (idx >> 13) & 7, ks = (idx >> 9) & 15;
    int l = (idx >> 3) & 63, j = idx & 7;
    int n = 32*w + (l & 31);
    int i = ks*16 + (l >> 5)*8 + j;
    const float* w3 = c ? w3b : w3a;
    float s = 0.f;
    #pragma unroll
    for (int q = 0; q < 8; ++q) {
      float sg2 = ((i >> (7-q)) & 1) ? -1.f : 1.f;
      s += sg2 * w3[q*256 + n];
    }
    Gm[idx] = f2bf(s);
  }
}

// ---------------------------------------------------------------------------
// enc_mfma: unchanged from R9 (32 rows/block, 4 waves/SIMD).
// ---------------------------------------------------------------------------
__global__ __launch_bounds__(256, 4)
void enc_mfma(const float* __restrict__ state, const float* __restrict__ action,
              const unsigned short* __restrict__ w1p,
              const float* __restrict__ b1a, const float* __restrict__ b1b,
              const unsigned short* __restrict__ w2p,
              const float* __restrict__ b2a, const float* __restrict__ b2b,
              float* __restrict__ enc, int Bn) {
  __shared__ __align__(16) char Bx[2][8192];
  __shared__ __align__(16) float sb1[2][256];
  __shared__ float sb2[2][8];
  __shared__ __align__(16) float encw[4][32][8];
  int tid = threadIdx.x;
  int lane = tid & 63, w = tid >> 6, il = lane & 31, h5 = lane >> 5;
  int r0 = blockIdx.x * 32;

  sb1[0][tid] = b1a[tid];
  sb1[1][tid] = b1b[tid];
  if (tid < 8) { sb2[0][tid] = b2a[tid]; sb2[1][tid] = b2b[tid]; }

  {
    int m = tid >> 3, q8 = tid & 7;
    const float4* st4 = (const float4*)state;
    const float4* ac4 = (const float4*)action;
    #pragma unroll
    for (int j = 0; j < 4; ++j) {
      int f = j*8 + q8;                 // float4 slot 0..31 of the row
      int ks = f >> 2, kq = f & 3;
      float4 v = (ks < 6) ? st4[(size_t)(r0+m)*24 + ks*4 + kq]
                          : ac4[(size_t)(r0+m)*8 + (ks-6)*4 + kq];
      unsigned short hx = f2bf(v.x), hy = f2bf(v.y), hz = f2bf(v.z), hw = f2bf(v.w);
      uint2 hh, ll;
      hh.x = (unsigned)hx | ((unsigned)hy << 16);
      hh.y = (unsigned)hz | ((unsigned)hw << 16);
      ll.x = (unsigned)f2bf(v.x - bf2f(hx)) | ((unsigned)f2bf(v.y - bf2f(hy)) << 16);
      ll.y = (unsigned)f2bf(v.z - bf2f(hz)) | ((unsigned)f2bf(v.w - bf2f(hw)) << 16);
      int off = ks*1024 + m*32 + kq*8;
      *(uint2*)(&Bx[0][off]) = hh;
      *(uint2*)(&Bx[1][off]) = ll;
    }
  }
  __syncthreads();

  for (int c = 0; c < 2; ++c) {
    accv_t A[2] = {{},{}};
    #pragma unroll
    for (int ks = 0; ks < 8; ++ks) {
      bfrag_t a0h, a0l, a1h, a1l;
      {
        size_t b0 = ((size_t)((c*2+0)*8 + ks)*2 + h5)*256;
        size_t b1 = ((size_t)((c*2+1)*8 + ks)*2 + h5)*256;
        int t0 = 2*w, t1 = 2*w+1;
        a0h = *(const bfrag_t*)(w1p + (b0 + t0*32 + il)*8);
        a0l = *(const bfrag_t*)(w1p + (b1 + t0*32 + il)*8);
        a1h = *(const bfrag_t*)(w1p + (b0 + t1*32 + il)*8);
        a1l = *(const bfrag_t*)(w1p + (b1 + t1*32 + il)*8);
      }
      bfrag_t b0h = *(const bfrag_t*)(&Bx[0][ks*1024 + il*32 + h5*16]);
      bfrag_t b0l = *(const bfrag_t*)(&Bx[1][ks*1024 + il*32 + h5*16]);
      A[0] = __builtin_amdgcn_mfma_f32_32x32x16_bf16(a0h, b0h, A[0], 0,0,0);
      A[0] = __builtin_amdgcn_mfma_f32_32x32x16_bf16(a0h, b0l, A[0], 0,0,0);
      A[0] = __builtin_amdgcn_mfma_f32_32x32x16_bf16(a0l, b0h, A[0], 0,0,0);
      A[1] = __builtin_amdgcn_mfma_f32_32x32x16_bf16(a1h, b0h, A[1], 0,0,0);
      A[1] = __builtin_amdgcn_mfma_f32_32x32x16_bf16(a1h, b0l, A[1], 0,0,0);
      A[1] = __builtin_amdgcn_mfma_f32_32x32x16_bf16(a1l, b0h, A[1], 0,0,0);
    }
    #pragma unroll
    for (int nt = 0; nt < 2; ++nt) {
      #pragma unroll
      for (int g = 0; g < 4; ++g) {
        float4 bb = *(const float4*)&sb1[c][(2*w+nt)*32 + 8*g + 4*h5];
        float bba[4] = {bb.x, bb.y, bb.z, bb.w};
        #pragma unroll
        for (int jj = 0; jj < 4; ++jj) {
          A[nt][4*g+jj] = fmaxf(A[nt][4*g+jj] + bba[jj], 0.f);
        }
      }
    }
    accv_t Cm = {};
    #pragma unroll
    for (int k2 = 0; k2 < 4; ++k2) {
      int k16 = 4*w + k2;
      bfrag_t g2h = *(const bfrag_t*)(w2p + ((size_t)((c*2+0)*16 + k16)*2 + h5)*256 + il*8);
      bfrag_t g2l = *(const bfrag_t*)(w2p + ((size_t)((c*2+1)*16 + k16)*2 + h5)*256 + il*8);
      unsigned ph[2][2], pl[2][2];
      #pragma unroll
      for (int gi = 0; gi < 2; ++gi) {
        int G = 2*k2 + gi, nt = G >> 2, g = G & 3;
        float f0 = A[nt][4*g+0], f1 = A[nt][4*g+1];
        float f2 = A[nt][4*g+2], f3 = A[nt][4*g+3];
        unsigned short h0 = f2bf(f0), h1 = f2bf(f1), h2 = f2bf(f2), h3 = f2bf(f3);
        ph[gi][0] = (unsigned)h0 | ((unsigned)h1 << 16);
        ph[gi][1] = (unsigned)h2 | ((unsigned)h3 << 16);
        pl[gi][0] = (unsigned)f2bf(f0 - bf2f(h0)) | ((unsigned)f2bf(f1 - bf2f(h1)) << 16);
        pl[gi][1] = (unsigned)f2bf(f2 - bf2f(h2)) | ((unsigned)f2bf(f3 - bf2f(h3)) << 16);
      }
      union { bfrag_t v; unsigned u[4]; } FH, FL;
      #pragma unroll
      for (int r = 0; r < 2; ++r) {
        unsigned own_h = h5 ? ph[1][r] : ph[0][r];
        unsigned alt_h = h5 ? ph[0][r] : ph[1][r];
        unsigned rec_h = __shfl_xor((int)alt_h, 32);
        FH.u[r]   = h5 ? rec_h : own_h;
        FH.u[2+r] = h5 ? own_h : rec_h;
        unsigned own_l = h5 ? pl[1][r] : pl[0][r];
        unsigned alt_l = h5 ? pl[0][r] : pl[1][r];
        unsigned rec_l = __shfl_xor((int)alt_l, 32);
        FL.u[r]   = h5 ? rec_l : own_l;
        FL.u[2+r] = h5 ? own_l : rec_l;
      }
      Cm = __builtin_amdgcn_mfma_f32_32x32x16_bf16(g2h, FH.v, Cm, 0,0,0);
      Cm = __builtin_amdgcn_mfma_f32_32x32x16_bf16(g2h, FL.v, Cm, 0,0,0);
      Cm = __builtin_amdgcn_mfma_f32_32x32x16_bf16(g2l, FH.v, Cm, 0,0,0);
    }
    *(float4*)&encw[w][il][4*h5] = make_float4(Cm[0], Cm[1], Cm[2], Cm[3]);
    __syncthreads();
    {
      int e = tid & 7, mm = tid >> 3;
      float v = sb2[c][e];
      #pragma unroll
      for (int ww = 0; ww < 4; ++ww) v += encw[ww][mm][e];
      enc[((size_t)c*Bn + r0 + mm)*8 + e] = v;
    }
    __syncthreads();
  }
}

// ---------------------------------------------------------------------------
// qgemm R10: R6 structure, phase1 subtile chains MERGED (4 accumulators,
// 2 independent dep-chains hide ds_read latency). FP order per-acc identical.
// ---------------------------------------------------------------------------
__device__ __forceinline__ void a_build(float4 ea, float4 eb, char* Ab, int ag2, int am) {
  float c0,s0,c1,s1,c2,s2,c3,s3,c4,s4,c5,s5,c6,s6,c7,s7;
  __sincosf(0.5f*ea.x, &s0, &c0);
  __sincosf(0.5f*ea.y, &s1, &c1);
  __sincosf(0.5f*ea.z, &s2, &c2);
  __sincosf(0.5f*ea.w, &s3, &c3);
  __sincosf(0.5f*eb.x, &s4, &c4);
  __sincosf(0.5f*eb.y, &s5, &c5);
  __sincosf(0.5f*eb.z, &s6, &c6);
  __sincosf(0.5f*eb.w, &s7, &c7);
  float v0 = (ag2&8) ? s0 : c0;
  float v1 = (ag2&4) ? s1 : c1;
  float v2 = (ag2&2) ? s2 : c2;
  float v3 = (ag2&1) ? s3 : c3;
  float top = v0*v1*v2*v3;
  float hA = top*c4, hB = top*s4;
  float p67[4];
  p67[0] = c6*c7; p67[1] = c6*s7; p67[2] = s6*c7; p67[3] = s6*s7;
  float low[8];
  #pragma unroll
  for (int j = 0; j < 8; ++j) low[j] = ((j&4) ? s5 : c5) * p67[j&3];
  union { bfrag_t v; unsigned u[4]; } pk;
  #pragma unroll
  for (int k = 0; k < 4; ++k) pk.u[k] = pack2(hA*low[2*k], hA*low[2*k+1]);
  *(bfrag_t*)(Ab + ag2*1024 + am*16) = pk.v;
  #pragma unroll
  for (int k = 0; k < 4; ++k) pk.u[k] = pack2(hB*low[2*k], hB*low[2*k+1]);
  *(bfrag_t*)(Ab + ag2*1024 + 512 + am*16) = pk.v;
}

__global__ __launch_bounds__(512, 2)
void qgemm(const float* __restrict__ enc,
           const unsigned short* __restrict__ Bm, const unsigned short* __restrict__ Gm,
           const float* __restrict__ b3a, const float* __restrict__ w4a, const float* __restrict__ b4a,
           const float* __restrict__ b3b, const float* __restrict__ w4b, const float* __restrict__ b4b,
           float* __restrict__ out, int Bn) {
  __shared__ __align__(16) char APq[132096];
  char* A0 = APq;                        // [g2*1024 + half*512 + m*16]
  char* A1 = APq + 16384;
  char* P0 = APq + 32768;                // [ks*1056 + lane*16]
  char* P1 = APq + 49664;
  float* qtmp = (float*)(APq + 66560);   // [64][256] fp32, dedicated

  int tid = threadIdx.x;
  int lane = tid & 63;
  int w = tid >> 6;
  int il = lane & 31;
  int h5 = lane >> 5;

  int c = blockIdx.x >> 7;
  int rowblock = blockIdx.x & 127;
  int rowsPerBlock = Bn >> 7;        // 512
  int npairs = rowsPerBlock >> 6;    // 8

  // ---- persistent W-frags: tile pair (w, 8+w), 128 regs ----
  bfrag_t bf0[16], bf1[16];
  {
    const unsigned short* base = Bm + ((size_t)(c*512 + 32*w + il)*256 + h5*8);
    #pragma unroll
    for (int ks = 0; ks < 16; ++ks) {
      bf0[ks] = *(const bfrag_t*)(base + ks*16);
      bf1[ks] = *(const bfrag_t*)(base + 256*256 + ks*16);
    }
  }
  int n2 = 32*w + il;
  const float* b3c = c ? b3b : b3a;
  const float* w4c = c ? w4b : w4a;
  const float* b4c = c ? b4b : b4a;
  float b3v = b3c[n2];
  float w4v = w4c[n2];
  float b4v = b4c[0];
  // coalesced G frag base for this wave's col-tile (row-invariant!)
  const unsigned short* Gbase = Gm + ((size_t)(c*8 + w)*16)*512 + lane*8;
  int pwbase = (n2>>4)*1056 + ((n2>>3)&1)*512 + (n2&7)*2;
  int rowAdd = 4*h5;

  int am = tid & 31, ag2 = tid >> 5;
  const float* encb = enc + ((size_t)c*Bn)*8;
  int rbase = rowblock*rowsPerBlock;

  // ---- prologue: A-build for first 64 rows ----
  {
    const float* ep0 = encb + (size_t)(rbase + am)*8;
    float4 pa0 = *(const float4*)ep0, pb0 = *(const float4*)(ep0 + 4);
    const float* ep1 = encb + (size_t)(rbase + 32 + am)*8;
    float4 pa1 = *(const float4*)ep1, pb1 = *(const float4*)(ep1 + 4);
    a_build(pa0, pb0, A0, ag2, am);
    a_build(pa1, pb1, A1, ag2, am);
  }
  __syncthreads();

  for (int st2 = 0; st2 < npairs; ++st2) {
    int r0 = rbase + st2*64;
    // ======= phase1: stage1 BOTH subtiles, merged (2 indep dep-chains) =====
    {
      accv_t a00 = {}, a01 = {}, a10 = {}, a11 = {};
      #pragma unroll
      for (int ks = 0; ks < 16; ++ks) {
        bfrag_t af0 = *(const bfrag_t*)(A0 + ks*1024 + lane*16);
        bfrag_t af1 = *(const bfrag_t*)(A1 + ks*1024 + lane*16);
        a00 = __builtin_amdgcn_mfma_f32_32x32x16_bf16(af0, bf0[ks], a00, 0, 0, 0);
        a01 = __builtin_amdgcn_mfma_f32_32x32x16_bf16(af0, bf1[ks], a01, 0, 0, 0);
        a10 = __builtin_amdgcn_mfma_f32_32x32x16_bf16(af1, bf0[ks], a10, 0, 0, 0);
        a11 = __builtin_amdgcn_mfma_f32_32x32x16_bf16(af1, bf1[ks], a11, 0, 0, 0);
      }
      #pragma unroll
      for (int r = 0; r < 16; ++r) {
        int row = (r&3) + 8*(r>>2) + rowAdd;
        float Pa = a00[r]*a00[r] + a01[r]*a01[r];
        float Pb = a10[r]*a10[r] + a11[r]*a11[r];
        *(unsigned short*)(P0 + pwbase + row*16) = f2bf(Pa);
        *(unsigned short*)(P1 + pwbase + row*16) = f2bf(Pb);
      }
    }
    __syncthreads();                                   // B2: P ready, A reads done
    // ================= phase2: stage2 both subtiles + A-build(next) ====
    float4 na0, nb0, na1, nb1;
    bool more = (st2 + 1 < npairs);
    if (more) {
      const float* ep0 = encb + (size_t)(r0 + 64 + am)*8;
      na0 = *(const float4*)ep0; nb0 = *(const float4*)(ep0 + 4);
      const float* ep1 = encb + (size_t)(r0 + 96 + am)*8;
      na1 = *(const float4*)ep1; nb1 = *(const float4*)(ep1 + 4);
    }
    accv_t acc2a = {}, acc2b = {};
    #pragma unroll 4
    for (int ks = 0; ks < 16; ++ks) {
      bfrag_t gf  = *(const bfrag_t*)(Gbase + ks*512);
      bfrag_t pf0 = *(const bfrag_t*)(P0 + ks*1056 + lane*16);
      bfrag_t pf1 = *(const bfrag_t*)(P1 + ks*1056 + lane*16);
      acc2a = __builtin_amdgcn_mfma_f32_32x32x16_bf16(pf0, gf, acc2a, 0, 0, 0);
      acc2b = __builtin_amdgcn_mfma_f32_32x32x16_bf16(pf1, gf, acc2b, 0, 0, 0);
    }
    #pragma unroll
    for (int r = 0; r < 16; ++r) {
      int row = (r&3) + 8*(r>>2) + rowAdd;
      qtmp[row*256 + n2]        = fmaxf(acc2a[r] + b3v, 0.f) * w4v;
      qtmp[(32 + row)*256 + n2] = fmaxf(acc2b[r] + b3v, 0.f) * w4v;
    }
    if (more) {
      a_build(na0, nb0, A0, ag2, am);
      a_build(na1, nb1, A1, ag2, am);
    }
    __syncthreads();                                   // B3: qtmp + next-A ready
    // ================= phase3: reduce 64 rows =================
    {
      int row = tid >> 3, seg = tid & 7;
      const float* qrow = qtmp + row*256;
      float s = 0.f;
      #pragma unroll
      for (int t = 0; t < 8; ++t) {
        float4 a = *(const float4*)(qrow + t*32 + seg*4);
        s += (a.x + a.y) + (a.z + a.w);
      }
      s += __shfl_xor(s, 1);
      s += __shfl_xor(s, 2);
      s += __shfl_xor(s, 4);
      if (seg == 0) out[(size_t)c*Bn + r0 + row] = s + b4v;
    }
    // no barrier: next phase1 touches only A/P; qtmp reuse is after next B2.
  }
}

extern "C" void kernel_launch(void* const* d_in, const int* in_sizes, int n_in,
                              void* d_out, int out_size, void* d_ws, size_t ws_size,
                              hipStream_t stream) {
  (void)n_in; (void)out_size; (void)ws_size;
  const float* state  = (const float*)d_in[0];
  const float* action = (const float*)d_in[1];
  const float* w1a=(const float*)d_in[2];  const float* b1a=(const float*)d_in[3];
  const float* w2a=(const float*)d_in[4];  const float* b2a=(const float*)d_in[5];
  const float* qrxa=(const float*)d_in[6]; const float* qrya=(const float*)d_in[7];
  const float* qrza=(const float*)d_in[8];
  const float* w3a=(const float*)d_in[9];  const float* b3a=(const float*)d_in[10];
  const float* w4a=(const float*)d_in[11]; const float* b4a=(const float*)d_in[12];
  const float* w1b=(const float*)d_in[13]; const float* b1b=(const float*)d_in[14];
  const float* w2b=(const float*)d_in[15]; const float* b2b=(const float*)d_in[16];
  const float* qrxb=(const float*)d_in[17];const float* qryb=(const float*)d_in[18];
  const float* qrzb=(const float*)d_in[19];
  const float* w3b=(const float*)d_in[20]; const float* b3b=(const float*)d_in[21];
  const float* w4b=(const float*)d_in[22]; const float* b4b=(const float*)d_in[23];

  int B = in_sizes[0] / 96;
  char* wsb = (char*)d_ws;
  unsigned short* Bmat = (unsigned short*)(wsb);                 // 524288 B
  unsigned short* Gmat = (unsigned short*)(wsb + 524288);        // 262144 B
  unsigned short* w1p  = (unsigned short*)(wsb + 786432);        // 262144 B
  unsigned short* w2p  = (unsigned short*)(wsb + 1048576);       // 65536 B
  float* enc           = (float*)(wsb + 1114112);                // 2*B*8*4 B

  prep_weights<<<712, 256, 0, stream>>>(qrxa,qrya,qrza,qrxb,qryb,qrzb,
                                        w1a,w1b,w2a,w2b,w3a,w3b,
                                        Bmat,Gmat,w1p,w2p);
  enc_mfma<<<B/32, 256, 0, stream>>>(state,action,w1p,b1a,b1b,w2p,b2a,b2b,enc,B);
  qgemm<<<256, 512, 0, stream>>>(enc, Bmat, Gmat, b3a, w4a, b4a, b3b, w4b, b4b,
                                 (float*)d_out, B);
}

// Round 8
// 204.235 us; speedup vs baseline: 1.1761x; 1.1761x over previous
//
#include <hip/hip_runtime.h>
#include <math.h>

// ---------------------------------------------------------------------------
// QuantumCritic R11.
//   psi = W r ; P = |psi|^2 ; ex[q] = sum_i sign(i,q) P[i] (S = +-1, rank-8!)
//   h2 = relu(ex @ w3 + b3) ; q = h2 . w4 + b4
// R11 changes vs R9 (R10 post-mortem: 4-acc merge spilled to scratch —
// WRITE_SIZE 512->10240KB. Scheduling levers exhausted at 2 waves/SIMD;
// this round REDUCES WORK using G = S^T w3 rank-8 structure):
//   - qgemm stage1 operands SWAPPED: acc = mfma(bf, af) (A/B frag lane
//     layouts are symmetric) -> lane now holds P over 16 i-values (i_local
//     bits: 0-1=r&3, 2=h5, 3-4=r>>2; 5-7=w). ex partials = T and 4 bit-sums
//     (~50 VALU) + h5/w sign flips + shfl_xor(32) combine.
//   - cross-wave: exw[sub][w][m][q] f32 (m-stride 9 f32: conflict-free
//     scalar writes) -> reduce 512 thr -> exf[sub][m][q] (stride 12 f32).
//   - stage2: ONE mfma per subtile: A = ex packed bf16 (K=16, rows 8-15
//     zero), B = w3-frag resident in 4 VGPRs (prep builds Gm2, h5=0 rows
//     w3[j][n], h5=1 zero). Deletes P LDS roundtrip + G streaming +
//     15/16 of stage2 MFMAs. acc2 layout unchanged -> qtmp epilogue
//     byte-identical to R9.
//   - 3 barriers/iter (exw | exf+A-build | qtmp). LDS 117KB.
// ---------------------------------------------------------------------------

typedef __attribute__((ext_vector_type(8))) short bfrag_t;   // 8 bf16 = 4 VGPR
typedef __attribute__((ext_vector_type(16))) float accv_t;   // 32x32 MFMA acc

__device__ __forceinline__ unsigned short f2bf(float x) {
  unsigned u = __float_as_uint(x);
  u += 0x7FFFu + ((u >> 16) & 1u);      // RNE
  return (unsigned short)(u >> 16);
}
__device__ __forceinline__ float bf2f(unsigned short h) {
  return __uint_as_float(((unsigned)h) << 16);
}
__device__ __forceinline__ unsigned pack2(float a, float b) {
  return (unsigned)f2bf(a) | ((unsigned)f2bf(b) << 16);
}

struct C2 { float r, i; };
__device__ __forceinline__ C2 cmul(C2 a, C2 b){ return C2{a.r*b.r - a.i*b.i, a.r*b.i + a.i*b.r}; }
__device__ __forceinline__ C2 cadd(C2 a, C2 b){ return C2{a.r+b.r, a.i+b.i}; }

#define APPLY2(A,Bx)                                                        \
  { float ar=re[A], ai=im[A], br=re[Bx], bi=im[Bx];                         \
    re[A]  = u00r*ar - u00i*ai + u01r*br - u01i*bi;                         \
    im[A]  = u00r*ai + u00i*ar + u01r*bi + u01i*br;                         \
    re[Bx] = u10r*ar - u10i*ai + u11r*br - u11i*bi;                         \
    im[Bx] = u10r*ai + u10i*ar + u11r*bi + u11i*br; }

__global__ __launch_bounds__(256)
void prep_weights(const float* __restrict__ qrxa, const float* __restrict__ qrya,
                  const float* __restrict__ qrza,
                  const float* __restrict__ qrxb, const float* __restrict__ qryb,
                  const float* __restrict__ qrzb,
                  const float* __restrict__ w1a, const float* __restrict__ w1b,
                  const float* __restrict__ w2a, const float* __restrict__ w2b,
                  const float* __restrict__ w3a, const float* __restrict__ w3b,
                  unsigned short* __restrict__ Bm, unsigned short* __restrict__ Gm,
                  unsigned short* __restrict__ w1p, unsigned short* __restrict__ w2p) {
  int blk = blockIdx.x;
  int tid = threadIdx.x;
  if (blk < 128) {
    // ---- prep_W: circuit on 256 basis columns ----
    __shared__ float sg[192];
    int c = blk >> 6;
    if (tid < 24) {
      const float* qx = c ? qrxb : qrxa;
      const float* qy = c ? qryb : qrya;
      const float* qz = c ? qrzb : qrza;
      int g = tid;
      float tx = 0.5f*qx[g], ty = 0.5f*qy[g], tz = 0.5f*qz[g];
      float cx = cosf(tx), sx = sinf(tx);
      float cy = cosf(ty), sy = sinf(ty);
      float cz = cosf(tz), sz = sinf(tz);
      C2 rx00{cx,0.f}, rx01{0.f,-sx}, rx10{0.f,-sx}, rx11{cx,0.f};
      C2 m00 = cadd(cmul(C2{cy,0.f},rx00), cmul(C2{-sy,0.f},rx10));
      C2 m01 = cadd(cmul(C2{cy,0.f},rx01), cmul(C2{-sy,0.f},rx11));
      C2 m10 = cadd(cmul(C2{sy,0.f},rx00), cmul(C2{cy,0.f},rx10));
      C2 m11 = cadd(cmul(C2{sy,0.f},rx01), cmul(C2{cy,0.f},rx11));
      C2 e0{cz,-sz}, e1{cz,sz};
      C2 u00 = cmul(e0,m00), u01 = cmul(e0,m01), u10 = cmul(e1,m10), u11 = cmul(e1,m11);
      float* o = sg + g*8;
      o[0]=u00.r; o[1]=u00.i; o[2]=u01.r; o[3]=u01.i;
      o[4]=u10.r; o[5]=u10.i; o[6]=u11.r; o[7]=u11.i;
    }
    __syncthreads();
    int lane = tid & 63;
    int wid = blk*4 + (tid >> 6);
    int bcol = wid & 255;
    int p = __popc(bcol) & 3;
    float phr = (p==0) ? 1.f : ((p==2) ? -1.f : 0.f);
    float phi = (p==1) ? -1.f : ((p==3) ? 1.f : 0.f);
    float re[4], im[4];
    #pragma unroll
    for (int j = 0; j < 4; ++j) {
      int idx = 4*lane + j;
      re[j] = (idx==bcol) ? phr : 0.f;
      im[j] = (idx==bcol) ? phi : 0.f;
    }
    #pragma unroll
    for (int l = 0; l < 3; ++l) {
      #pragma unroll
      for (int q = 0; q < 8; ++q) {
        const float* u = &sg[(size_t)(l*8 + q)*8];
        float u00r=u[0],u00i=u[1],u01r=u[2],u01i=u[3];
        float u10r=u[4],u10i=u[5],u11r=u[6],u11i=u[7];
        if (q < 6) {
          int m = 5-q, mask = 1<<m;
          bool s1 = ((lane >> m) & 1) != 0;
          float udr = s1?u11r:u00r, udi = s1?u11i:u00i;
          float uor = s1?u10r:u01r, uoi = s1?u10i:u01i;
          #pragma unroll
          for (int j = 0; j < 4; ++j) {
            float pr = __shfl_xor(re[j], mask);
            float pi = __shfl_xor(im[j], mask);
            float nr = udr*re[j] - udi*im[j] + uor*pr - uoi*pi;
            float ni = udr*im[j] + udi*re[j] + uor*pi + uoi*pr;
            re[j]=nr; im[j]=ni;
          }
        } else if (q == 6) { APPLY2(0,2); APPLY2(1,3); }
        else               { APPLY2(0,1); APPLY2(2,3); }
      }
      #pragma unroll
      for (int cq = 0; cq <= 4; ++cq) {
        int tmask = 1 << (4-cq);
        bool pred = ((lane >> (5-cq)) & 1) != 0;
        #pragma unroll
        for (int j = 0; j < 4; ++j) {
          float sr = __shfl_xor(re[j], tmask);
          float si = __shfl_xor(im[j], tmask);
          re[j] = pred ? sr : re[j];
          im[j] = pred ? si : im[j];
        }
      }
      { bool pred = (lane & 1) != 0;
        float t0, t1;
        t0 = pred?re[2]:re[0]; t1 = pred?re[0]:re[2]; re[0]=t0; re[2]=t1;
        t0 = pred?im[2]:im[0]; t1 = pred?im[0]:im[2]; im[0]=t0; im[2]=t1;
        t0 = pred?re[3]:re[1]; t1 = pred?re[1]:re[3]; re[1]=t0; re[3]=t1;
        t0 = pred?im[3]:im[1]; t1 = pred?im[1]:im[3]; im[1]=t0; im[3]=t1; }
      { float t;
        t=re[2]; re[2]=re[3]; re[3]=t;
        t=im[2]; im[2]=im[3]; im[3]=t; }
      { re[1]=__shfl_xor(re[1],32); im[1]=__shfl_xor(im[1],32);
        re[3]=__shfl_xor(re[3],32); im[3]=__shfl_xor(im[3],32); }
    }
    #pragma unroll
    for (int j = 0; j < 4; ++j) {
      int i = 4*lane + j;
      Bm[(size_t)(c*512 + i)*256 + bcol]       = f2bf(re[j]);
      Bm[(size_t)(c*512 + 256 + i)*256 + bcol] = f2bf(im[j]);
    }
  } else if (blk < 192) {
    // ---- w1pack ----
    int slot = (blk-128)*256 + tid;
    int n = slot & 255, h5 = (slot>>8)&1, ks = (slot>>9)&7, p = (slot>>12)&1, c = slot>>13;
    const float* w1c = c ? w1b : w1a;
    #pragma unroll
    for (int j = 0; j < 8; ++j) {
      float v = w1c[(size_t)(ks*16 + h5*8 + j)*256 + n];
      unsigned short hi = f2bf(v);
      w1p[(size_t)slot*8 + j] = p ? f2bf(v - bf2f(hi)) : hi;
    }
  } else if (blk < 200) {
    // ---- w2pack ----
    int slot = (blk-192)*256 + tid;
    int combo = slot >> 4, part = slot & 15;
    int h5 = combo&1, k16 = (combo>>1)&15, p = (combo>>5)&1, c = (combo>>6)&1;
    const float* w2c = c ? w2b : w2a;
    #pragma unroll
    for (int jj = 0; jj < 16; ++jj) {
      int idx = part*16 + jj;
      int il = idx >> 3, j = idx & 7;
      int n = k16*16 + h5*8 + j;
      float v = (il < 8) ? w2c[(size_t)n*8 + il] : 0.f;
      unsigned short hi = f2bf(v);
      w2p[(size_t)combo*256 + idx] = p ? f2bf(v - bf2f(hi)) : hi;
    }
  } else {
    // ---- Gm2: w3 B-frags for rank-8 stage2.
    // Gm[((c*8+w)*64+lane)*8+j] = (lane<32) ? bf16(w3[j][32w+(lane&31)]) : 0
    // (B-frag: col n = lane&31, k = (lane>>5)*8+j; K rows 8..15 are zero pad)
    int idx = (blk-200)*256 + tid;          // [0, 8192)
    int j = idx & 7, lane = (idx >> 3) & 63, w = (idx >> 9) & 7, c = (idx >> 12) & 1;
    int h5 = lane >> 5, il = lane & 31;
    int n = 32*w + il;
    const float* w3 = c ? w3b : w3a;
    Gm[idx] = h5 ? (unsigned short)0 : f2bf(w3[j*256 + n]);
  }
}

// ---------------------------------------------------------------------------
// enc_mfma: unchanged from R9 (32 rows/block, 4 waves/SIMD).
// ---------------------------------------------------------------------------
__global__ __launch_bounds__(256, 4)
void enc_mfma(const float* __restrict__ state, const float* __restrict__ action,
              const unsigned short* __restrict__ w1p,
              const float* __restrict__ b1a, const float* __restrict__ b1b,
              const unsigned short* __restrict__ w2p,
              const float* __restrict__ b2a, const float* __restrict__ b2b,
              float* __restrict__ enc, int Bn) {
  __shared__ __align__(16) char Bx[2][8192];
  __shared__ __align__(16) float sb1[2][256];
  __shared__ float sb2[2][8];
  __shared__ __align__(16) float encw[4][32][8];
  int tid = threadIdx.x;
  int lane = tid & 63, w = tid >> 6, il = lane & 31, h5 = lane >> 5;
  int r0 = blockIdx.x * 32;

  sb1[0][tid] = b1a[tid];
  sb1[1][tid] = b1b[tid];
  if (tid < 8) { sb2[0][tid] = b2a[tid]; sb2[1][tid] = b2b[tid]; }

  {
    int m = tid >> 3, q8 = tid & 7;
    const float4* st4 = (const float4*)state;
    const float4* ac4 = (const float4*)action;
    #pragma unroll
    for (int j = 0; j < 4; ++j) {
      int f = j*8 + q8;                 // float4 slot 0..31 of the row
      int ks = f >> 2, kq = f & 3;
      float4 v = (ks < 6) ? st4[(size_t)(r0+m)*24 + ks*4 + kq]
                          : ac4[(size_t)(r0+m)*8 + (ks-6)*4 + kq];
      unsigned short hx = f2bf(v.x), hy = f2bf(v.y), hz = f2bf(v.z), hw = f2bf(v.w);
      uint2 hh, ll;
      hh.x = (unsigned)hx | ((unsigned)hy << 16);
      hh.y = (unsigned)hz | ((unsigned)hw << 16);
      ll.x = (unsigned)f2bf(v.x - bf2f(hx)) | ((unsigned)f2bf(v.y - bf2f(hy)) << 16);
      ll.y = (unsigned)f2bf(v.z - bf2f(hz)) | ((unsigned)f2bf(v.w - bf2f(hw)) << 16);
      int off = ks*1024 + m*32 + kq*8;
      *(uint2*)(&Bx[0][off]) = hh;
      *(uint2*)(&Bx[1][off]) = ll;
    }
  }
  __syncthreads();

  for (int c = 0; c < 2; ++c) {
    accv_t A[2] = {{},{}};
    #pragma unroll
    for (int ks = 0; ks < 8; ++ks) {
      bfrag_t a0h, a0l, a1h, a1l;
      {
        size_t b0 = ((size_t)((c*2+0)*8 + ks)*2 + h5)*256;
        size_t b1 = ((size_t)((c*2+1)*8 + ks)*2 + h5)*256;
        int t0 = 2*w, t1 = 2*w+1;
        a0h = *(const bfrag_t*)(w1p + (b0 + t0*32 + il)*8);
        a0l = *(const bfrag_t*)(w1p + (b1 + t0*32 + il)*8);
        a1h = *(const bfrag_t*)(w1p + (b0 + t1*32 + il)*8);
        a1l = *(const bfrag_t*)(w1p + (b1 + t1*32 + il)*8);
      }
      bfrag_t b0h = *(const bfrag_t*)(&Bx[0][ks*1024 + il*32 + h5*16]);
      bfrag_t b0l = *(const bfrag_t*)(&Bx[1][ks*1024 + il*32 + h5*16]);
      A[0] = __builtin_amdgcn_mfma_f32_32x32x16_bf16(a0h, b0h, A[0], 0,0,0);
      A[0] = __builtin_amdgcn_mfma_f32_32x32x16_bf16(a0h, b0l, A[0], 0,0,0);
      A[0] = __builtin_amdgcn_mfma_f32_32x32x16_bf16(a0l, b0h, A[0], 0,0,0);
      A[1] = __builtin_amdgcn_mfma_f32_32x32x16_bf16(a1h, b0h, A[1], 0,0,0);
      A[1] = __builtin_amdgcn_mfma_f32_32x32x16_bf16(a1h, b0l, A[1], 0,0,0);
      A[1] = __builtin_amdgcn_mfma_f32_32x32x16_bf16(a1l, b0h, A[1], 0,0,0);
    }
    #pragma unroll
    for (int nt = 0; nt < 2; ++nt) {
      #pragma unroll
      for (int g = 0; g < 4; ++g) {
        float4 bb = *(const float4*)&sb1[c][(2*w+nt)*32 + 8*g + 4*h5];
        float bba[4] = {bb.x, bb.y, bb.z, bb.w};
        #pragma unroll
        for (int jj = 0; jj < 4; ++jj) {
          A[nt][4*g+jj] = fmaxf(A[nt][4*g+jj] + bba[jj], 0.f);
        }
      }
    }
    accv_t Cm = {};
    #pragma unroll
    for (int k2 = 0; k2 < 4; ++k2) {
      int k16 = 4*w + k2;
      bfrag_t g2h = *(const bfrag_t*)(w2p + ((size_t)((c*2+0)*16 + k16)*2 + h5)*256 + il*8);
      bfrag_t g2l = *(const bfrag_t*)(w2p + ((size_t)((c*2+1)*16 + k16)*2 + h5)*256 + il*8);
      unsigned ph[2][2], pl[2][2];
      #pragma unroll
      for (int gi = 0; gi < 2; ++gi) {
        int G = 2*k2 + gi, nt = G >> 2, g = G & 3;
        float f0 = A[nt][4*g+0], f1 = A[nt][4*g+1];
        float f2 = A[nt][4*g+2], f3 = A[nt][4*g+3];
        unsigned short h0 = f2bf(f0), h1 = f2bf(f1), h2 = f2bf(f2), h3 = f2bf(f3);
        ph[gi][0] = (unsigned)h0 | ((unsigned)h1 << 16);
        ph[gi][1] = (unsigned)h2 | ((unsigned)h3 << 16);
        pl[gi][0] = (unsigned)f2bf(f0 - bf2f(h0)) | ((unsigned)f2bf(f1 - bf2f(h1)) << 16);
        pl[gi][1] = (unsigned)f2bf(f2 - bf2f(h2)) | ((unsigned)f2bf(f3 - bf2f(h3)) << 16);
      }
      union { bfrag_t v; unsigned u[4]; } FH, FL;
      #pragma unroll
      for (int r = 0; r < 2; ++r) {
        unsigned own_h = h5 ? ph[1][r] : ph[0][r];
        unsigned alt_h = h5 ? ph[0][r] : ph[1][r];
        unsigned rec_h = __shfl_xor((int)alt_h, 32);
        FH.u[r]   = h5 ? rec_h : own_h;
        FH.u[2+r] = h5 ? own_h : rec_h;
        unsigned own_l = h5 ? pl[1][r] : pl[0][r];
        unsigned alt_l = h5 ? pl[0][r] : pl[1][r];
        unsigned rec_l = __shfl_xor((int)alt_l, 32);
        FL.u[r]   = h5 ? rec_l : own_l;
        FL.u[2+r] = h5 ? own_l : rec_l;
      }
      Cm = __builtin_amdgcn_mfma_f32_32x32x16_bf16(g2h, FH.v, Cm, 0,0,0);
      Cm = __builtin_amdgcn_mfma_f32_32x32x16_bf16(g2h, FL.v, Cm, 0,0,0);
      Cm = __builtin_amdgcn_mfma_f32_32x32x16_bf16(g2l, FH.v, Cm, 0,0,0);
    }
    *(float4*)&encw[w][il][4*h5] = make_float4(Cm[0], Cm[1], Cm[2], Cm[3]);
    __syncthreads();
    {
      int e = tid & 7, mm = tid >> 3;
      float v = sb2[c][e];
      #pragma unroll
      for (int ww = 0; ww < 4; ++ww) v += encw[ww][mm][e];
      enc[((size_t)c*Bn + r0 + mm)*8 + e] = v;
    }
    __syncthreads();
  }
}

// ---------------------------------------------------------------------------
// qgemm R11 helpers
// ---------------------------------------------------------------------------
__device__ __forceinline__ void a_build(float4 ea, float4 eb, char* Ab, int ag2, int am) {
  float c0,s0,c1,s1,c2,s2,c3,s3,c4,s4,c5,s5,c6,s6,c7,s7;
  __sincosf(0.5f*ea.x, &s0, &c0);
  __sincosf(0.5f*ea.y, &s1, &c1);
  __sincosf(0.5f*ea.z, &s2, &c2);
  __sincosf(0.5f*ea.w, &s3, &c3);
  __sincosf(0.5f*eb.x, &s4, &c4);
  __sincosf(0.5f*eb.y, &s5, &c5);
  __sincosf(0.5f*eb.z, &s6, &c6);
  __sincosf(0.5f*eb.w, &s7, &c7);
  float v0 = (ag2&8) ? s0 : c0;
  float v1 = (ag2&4) ? s1 : c1;
  float v2 = (ag2&2) ? s2 : c2;
  float v3 = (ag2&1) ? s3 : c3;
  float top = v0*v1*v2*v3;
  float hA = top*c4, hB = top*s4;
  float p67[4];
  p67[0] = c6*c7; p67[1] = c6*s7; p67[2] = s6*c7; p67[3] = s6*s7;
  float low[8];
  #pragma unroll
  for (int j = 0; j < 8; ++j) low[j] = ((j&4) ? s5 : c5) * p67[j&3];
  union { bfrag_t v; unsigned u[4]; } pk;
  #pragma unroll
  for (int k = 0; k < 4; ++k) pk.u[k] = pack2(hA*low[2*k], hA*low[2*k+1]);
  *(bfrag_t*)(Ab + ag2*1024 + am*16) = pk.v;
  #pragma unroll
  for (int k = 0; k < 4; ++k) pk.u[k] = pack2(hB*low[2*k], hB*low[2*k+1]);
  *(bfrag_t*)(Ab + ag2*1024 + 512 + am*16) = pk.v;
}

// ---------------------------------------------------------------------------
// qgemm R11: 512 thr = 8 waves, grid 256, 8 iters of 64 rows.
// Per iter: S1 both subtiles (swapped-operand MFMA, lane holds P over i;
// bit-sign sums -> exw partials) | B2 | exw->exf reduce + A-build(next) |
// B3 | stage2 (1 MFMA/subtile vs w3-frag) + qtmp | B4 | reduce -> out.
// LDS 117KB: A0/A1 32K | exw 18K | exf 3K | qtmp 64K.
// ---------------------------------------------------------------------------
__global__ __launch_bounds__(512, 2)
void qgemm(const float* __restrict__ enc,
           const unsigned short* __restrict__ Bm, const unsigned short* __restrict__ Gm,
           const float* __restrict__ b3a, const float* __restrict__ w4a, const float* __restrict__ b4a,
           const float* __restrict__ b3b, const float* __restrict__ w4b, const float* __restrict__ b4b,
           float* __restrict__ out, int Bn) {
  __shared__ __align__(16) char APq[119808];
  char* A0 = APq;                        // [g2*1024 + half*512 + m*16]
  char* A1 = APq + 16384;
  float* exw = (float*)(APq + 32768);    // [sub*2304 + w*288 + m*9 + q] f32
  float* exf = (float*)(APq + 51200);    // [sub*384 + m*12 + q] f32
  float* qtmp = (float*)(APq + 54272);   // [64][256] fp32

  int tid = threadIdx.x;
  int lane = tid & 63;
  int w = tid >> 6;
  int il = lane & 31;
  int h5 = lane >> 5;

  int c = blockIdx.x >> 7;
  int rowblock = blockIdx.x & 127;
  int rowsPerBlock = Bn >> 7;        // 512
  int npairs = rowsPerBlock >> 6;    // 8

  // ---- persistent W-frags: tile pair (w, 8+w), 128 regs ----
  bfrag_t bf0[16], bf1[16];
  {
    const unsigned short* base = Bm + ((size_t)(c*512 + 32*w + il)*256 + h5*8);
    #pragma unroll
    for (int ks = 0; ks < 16; ++ks) {
      bf0[ks] = *(const bfrag_t*)(base + ks*16);
      bf1[ks] = *(const bfrag_t*)(base + 256*256 + ks*16);
    }
  }
  // resident w3 B-frag (4 VGPRs)
  bfrag_t gf2 = *(const bfrag_t*)(Gm + ((size_t)((c*8 + w)*64 + lane))*8);

  int n2 = 32*w + il;
  const float* b3c = c ? b3b : b3a;
  const float* w4c = c ? w4b : w4a;
  const float* b4c = c ? b4b : b4a;
  float b3v = b3c[n2];
  float w4v = w4c[n2];
  float b4v = b4c[0];
  int rowAdd = 4*h5;

  int am = tid & 31, ag2 = tid >> 5;
  const float* encb = enc + ((size_t)c*Bn)*8;
  int rbase = rowblock*rowsPerBlock;

  // ---- prologue: A-build for first 64 rows ----
  {
    const float* ep0 = encb + (size_t)(rbase + am)*8;
    float4 pa0 = *(const float4*)ep0, pb0 = *(const float4*)(ep0 + 4);
    const float* ep1 = encb + (size_t)(rbase + 32 + am)*8;
    float4 pa1 = *(const float4*)ep1, pb1 = *(const float4*)(ep1 + 4);
    a_build(pa0, pb0, A0, ag2, am);
    a_build(pa1, pb1, A1, ag2, am);
  }
  __syncthreads();

  for (int st2 = 0; st2 < npairs; ++st2) {
    int r0 = rbase + st2*64;
    // ===== phase1: stage1 both subtiles, swapped operands; ex partials =====
    #pragma unroll
    for (int sub = 0; sub < 2; ++sub) {
      const char* Asel = sub ? A1 : A0;
      accv_t acc0 = {}, acc1 = {};
      #pragma unroll
      for (int ks = 0; ks < 16; ++ks) {
        bfrag_t af = *(const bfrag_t*)(Asel + ks*1024 + lane*16);
        acc0 = __builtin_amdgcn_mfma_f32_32x32x16_bf16(bf0[ks], af, acc0, 0, 0, 0);
        acc1 = __builtin_amdgcn_mfma_f32_32x32x16_bf16(bf1[ks], af, acc1, 0, 0, 0);
      }
      // lane holds P[i_local(r,h5)][m=il]; i bits: 0-1=r&3, 2=h5, 3-4=r>>2
      float Pv[16];
      #pragma unroll
      for (int r = 0; r < 16; ++r) Pv[r] = acc0[r]*acc0[r] + acc1[r]*acc1[r];
      float E  = ((Pv[0]+Pv[1])+(Pv[2]+Pv[3])) + ((Pv[4]+Pv[5])+(Pv[6]+Pv[7]));
      float S4 = ((Pv[8]+Pv[9])+(Pv[10]+Pv[11])) + ((Pv[12]+Pv[13])+(Pv[14]+Pv[15]));
      float T  = E + S4;
      float S0 = ((Pv[1]+Pv[3])+(Pv[5]+Pv[7])) + ((Pv[9]+Pv[11])+(Pv[13]+Pv[15]));
      float S1 = ((Pv[2]+Pv[3])+(Pv[6]+Pv[7])) + ((Pv[10]+Pv[11])+(Pv[14]+Pv[15]));
      float S3 = ((Pv[4]+Pv[5])+(Pv[6]+Pv[7])) + ((Pv[12]+Pv[13])+(Pv[14]+Pv[15]));
      float e[8];
      e[7] = T - 2.f*S0;           // q=7 <- i bit0
      e[6] = T - 2.f*S1;           // bit1
      e[5] = h5 ? -T : T;          // bit2 = h5
      e[4] = T - 2.f*S3;           // bit3
      e[3] = T - 2.f*S4;           // bit4
      e[2] = (w&1) ? -T : T;       // bit5
      e[1] = (w&2) ? -T : T;       // bit6
      e[0] = (w&4) ? -T : T;       // bit7
      #pragma unroll
      for (int q = 0; q < 8; ++q) e[q] += __shfl_xor(e[q], 32);
      if (h5 == 0) {
        float* dst = exw + sub*2304 + w*288 + il*9;
        #pragma unroll
        for (int q = 0; q < 8; ++q) dst[q] = e[q];
      }
    }
    __syncthreads();                                   // B2: exw ready, A reads done
    // ===== phase2: exw -> exf (8-wave sum) + A-build(next) =====
    float4 na0, nb0, na1, nb1;
    bool more = (st2 + 1 < npairs);
    if (more) {
      const float* ep0 = encb + (size_t)(r0 + 64 + am)*8;
      na0 = *(const float4*)ep0; nb0 = *(const float4*)(ep0 + 4);
      const float* ep1 = encb + (size_t)(r0 + 96 + am)*8;
      na1 = *(const float4*)ep1; nb1 = *(const float4*)(ep1 + 4);
    }
    {
      int sub = tid >> 8, m = (tid >> 3) & 31, q = tid & 7;
      const float* ew = exw + sub*2304 + m*9 + q;
      float s = ((ew[0] + ew[288]) + (ew[2*288] + ew[3*288]))
              + ((ew[4*288] + ew[5*288]) + (ew[6*288] + ew[7*288]));
      exf[sub*384 + m*12 + q] = s;
    }
    if (more) {
      a_build(na0, nb0, A0, ag2, am);
      a_build(na1, nb1, A1, ag2, am);
    }
    __syncthreads();                                   // B3: exf + next-A ready
    // ===== phase3: stage2 rank-8 (1 MFMA/subtile) + qtmp writes =====
    {
      union { bfrag_t v; unsigned u[4]; } fa, fb;
      if (h5 == 0) {
        const float* e0 = exf + il*12;
        float4 x0 = *(const float4*)(e0);
        float4 x1 = *(const float4*)(e0 + 4);
        fa.u[0] = pack2(x0.x, x0.y); fa.u[1] = pack2(x0.z, x0.w);
        fa.u[2] = pack2(x1.x, x1.y); fa.u[3] = pack2(x1.z, x1.w);
        const float* e1 = exf + 384 + il*12;
        float4 y0 = *(const float4*)(e1);
        float4 y1 = *(const float4*)(e1 + 4);
        fb.u[0] = pack2(y0.x, y0.y); fb.u[1] = pack2(y0.z, y0.w);
        fb.u[2] = pack2(y1.x, y1.y); fb.u[3] = pack2(y1.z, y1.w);
      } else {
        fa.u[0]=0; fa.u[1]=0; fa.u[2]=0; fa.u[3]=0;
        fb.u[0]=0; fb.u[1]=0; fb.u[2]=0; fb.u[3]=0;
      }
      accv_t acc2a = {}, acc2b = {};
      acc2a = __builtin_amdgcn_mfma_f32_32x32x16_bf16(fa.v, gf2, acc2a, 0, 0, 0);
      acc2b = __builtin_amdgcn_mfma_f32_32x32x16_bf16(fb.v, gf2, acc2b, 0, 0, 0);
      #pragma unroll
      for (int r = 0; r < 16; ++r) {
        int row = (r&3) + 8*(r>>2) + rowAdd;
        qtmp[row*256 + n2]        = fmaxf(acc2a[r] + b3v, 0.f) * w4v;
        qtmp[(32 + row)*256 + n2] = fmaxf(acc2b[r] + b3v, 0.f) * w4v;
      }
    }
    __syncthreads();                                   // B4: qtmp ready
    // ===== phase4: reduce 64 rows =====
    {
      int row = tid >> 3, seg = tid & 7;
      const float* qrow = qtmp + row*256;
      float s = 0.f;
      #pragma unroll
      for (int t = 0; t < 8; ++t) {
        float4 a = *(const float4*)(qrow + t*32 + seg*4);
        s += (a.x + a.y) + (a.z + a.w);
      }
      s += __shfl_xor(s, 1);
      s += __shfl_xor(s, 2);
      s += __shfl_xor(s, 4);
      if (seg == 0) out[(size_t)c*Bn + r0 + row] = s + b4v;
    }
    // loop: next stage1 writes exw (reads done pre-B3), reads A (built
    // phase2, B3+B4 since); qtmp reuse after next B2/B3. Safe.
  }
}

extern "C" void kernel_launch(void* const* d_in, const int* in_sizes, int n_in,
                              void* d_out, int out_size, void* d_ws, size_t ws_size,
                              hipStream_t stream) {
  (void)n_in; (void)out_size; (void)ws_size;
  const float* state  = (const float*)d_in[0];
  const float* action = (const float*)d_in[1];
  const float* w1a=(const float*)d_in[2];  const float* b1a=(const float*)d_in[3];
  const float* w2a=(const float*)d_in[4];  const float* b2a=(const float*)d_in[5];
  const float* qrxa=(const float*)d_in[6]; const float* qrya=(const float*)d_in[7];
  const float* qrza=(const float*)d_in[8];
  const float* w3a=(const float*)d_in[9];  const float* b3a=(const float*)d_in[10];
  const float* w4a=(const float*)d_in[11]; const float* b4a=(const float*)d_in[12];
  const float* w1b=(const float*)d_in[13]; const float* b1b=(const float*)d_in[14];
  const float* w2b=(const float*)d_in[15]; const float* b2b=(const float*)d_in[16];
  const float* qrxb=(const float*)d_in[17];const float* qryb=(const float*)d_in[18];
  const float* qrzb=(const float*)d_in[19];
  const float* w3b=(const float*)d_in[20]; const float* b3b=(const float*)d_in[21];
  const float* w4b=(const float*)d_in[22]; const float* b4b=(const float*)d_in[23];

  int B = in_sizes[0] / 96;
  char* wsb = (char*)d_ws;
  unsigned short* Bmat = (unsigned short*)(wsb);                 // 524288 B
  unsigned short* Gmat = (unsigned short*)(wsb + 524288);        // 16384 B used
  unsigned short* w1p  = (unsigned short*)(wsb + 786432);        // 262144 B
  unsigned short* w2p  = (unsigned short*)(wsb + 1048576);       // 65536 B
  float* enc           = (float*)(wsb + 1114112);                // 2*B*8*4 B

  prep_weights<<<232, 256, 0, stream>>>(qrxa,qrya,qrza,qrxb,qryb,qrzb,
                                        w1a,w1b,w2a,w2b,w3a,w3b,
                                        Bmat,Gmat,w1p,w2p);
  enc_mfma<<<B/32, 256, 0, stream>>>(state,action,w1p,b1a,b1b,w2p,b2a,b2b,enc,B);
  qgemm<<<256, 512, 0, stream>>>(enc, Bmat, Gmat, b3a, w4a, b4a, b3b, w4b, b4b,
                                 (float*)d_out, B);
}

// Round 9
// 202.961 us; speedup vs baseline: 1.1835x; 1.0063x over previous
//
#include <hip/hip_runtime.h>
#include <math.h>

// ---------------------------------------------------------------------------
// QuantumCritic R12.
//   psi = W r ; P = |psi|^2 ; ex[q] = sum_i sign(i,q) P[i] (rank-8)
//   q = sum_n sign(w4[n]) * relu(ex.(w3[:,n]|w4[n]|) + b3[n]|w4[n]|) + b4
// R12 changes vs R11 (post-mortem: qtmp round-trip = 2.3K DS cyc/iter + B4
// barrier; stage2 output had n on lanes -> cross-lane n-reduce forced LDS):
//   - stage2 operands swapped AGAIN: acc2 = mfma(gf2, fa) -> lane = batch m,
//     r = n-index. n-reduce = per-lane serial 16 adds (compile-time indexed)
//     + shfl_xor(32) + ONE scalar write to qp[64][9] (2.3KB).
//   - |w4| folded into Gm2 (relu(|w4|x) = |w4|relu(x)); sign applied
//     post-relu via __ballot(w4<0) mask bit (r&3)+8*(r>>2)+4*h5.
//   - b3*|w4| folded into the MFMA zero-pad row k=8: fa h5=1 j=0 = 1.0,
//     Gm2 h5=1 j=0 = b3[n]*|w4[n]|. Bias add free, no extra registers.
//   - out-write deferred: qp written phase3, reduced by 64 threads in NEXT
//     iter's phase2 (B2 orders it). B4 DELETED -> 2 barriers/iter.
//   - LDS 56.6KB (qtmp 64K freed): A0/A1 32K | exw 18K | exf 3K | qp 2.3K.
// ---------------------------------------------------------------------------

typedef __attribute__((ext_vector_type(8))) short bfrag_t;   // 8 bf16 = 4 VGPR
typedef __attribute__((ext_vector_type(16))) float accv_t;   // 32x32 MFMA acc

__device__ __forceinline__ unsigned short f2bf(float x) {
  unsigned u = __float_as_uint(x);
  u += 0x7FFFu + ((u >> 16) & 1u);      // RNE
  return (unsigned short)(u >> 16);
}
__device__ __forceinline__ float bf2f(unsigned short h) {
  return __uint_as_float(((unsigned)h) << 16);
}
__device__ __forceinline__ unsigned pack2(float a, float b) {
  return (unsigned)f2bf(a) | ((unsigned)f2bf(b) << 16);
}

struct C2 { float r, i; };
__device__ __forceinline__ C2 cmul(C2 a, C2 b){ return C2{a.r*b.r - a.i*b.i, a.r*b.i + a.i*b.r}; }
__device__ __forceinline__ C2 cadd(C2 a, C2 b){ return C2{a.r+b.r, a.i+b.i}; }

#define APPLY2(A,Bx)                                                        \
  { float ar=re[A], ai=im[A], br=re[Bx], bi=im[Bx];                         \
    re[A]  = u00r*ar - u00i*ai + u01r*br - u01i*bi;                         \
    im[A]  = u00r*ai + u00i*ar + u01r*bi + u01i*br;                         \
    re[Bx] = u10r*ar - u10i*ai + u11r*br - u11i*bi;                         \
    im[Bx] = u10r*ai + u10i*ar + u11r*bi + u11i*br; }

__global__ __launch_bounds__(256)
void prep_weights(const float* __restrict__ qrxa, const float* __restrict__ qrya,
                  const float* __restrict__ qrza,
                  const float* __restrict__ qrxb, const float* __restrict__ qryb,
                  const float* __restrict__ qrzb,
                  const float* __restrict__ w1a, const float* __restrict__ w1b,
                  const float* __restrict__ w2a, const float* __restrict__ w2b,
                  const float* __restrict__ w3a, const float* __restrict__ w3b,
                  const float* __restrict__ w4a, const float* __restrict__ w4b,
                  const float* __restrict__ b3a, const float* __restrict__ b3b,
                  unsigned short* __restrict__ Bm, unsigned short* __restrict__ Gm,
                  unsigned short* __restrict__ w1p, unsigned short* __restrict__ w2p) {
  int blk = blockIdx.x;
  int tid = threadIdx.x;
  if (blk < 128) {
    // ---- prep_W: circuit on 256 basis columns ----
    __shared__ float sg[192];
    int c = blk >> 6;
    if (tid < 24) {
      const float* qx = c ? qrxb : qrxa;
      const float* qy = c ? qryb : qrya;
      const float* qz = c ? qrzb : qrza;
      int g = tid;
      float tx = 0.5f*qx[g], ty = 0.5f*qy[g], tz = 0.5f*qz[g];
      float cx = cosf(tx), sx = sinf(tx);
      float cy = cosf(ty), sy = sinf(ty);
      float cz = cosf(tz), sz = sinf(tz);
      C2 rx00{cx,0.f}, rx01{0.f,-sx}, rx10{0.f,-sx}, rx11{cx,0.f};
      C2 m00 = cadd(cmul(C2{cy,0.f},rx00), cmul(C2{-sy,0.f},rx10));
      C2 m01 = cadd(cmul(C2{cy,0.f},rx01), cmul(C2{-sy,0.f},rx11));
      C2 m10 = cadd(cmul(C2{sy,0.f},rx00), cmul(C2{cy,0.f},rx10));
      C2 m11 = cadd(cmul(C2{sy,0.f},rx01), cmul(C2{cy,0.f},rx11));
      C2 e0{cz,-sz}, e1{cz,sz};
      C2 u00 = cmul(e0,m00), u01 = cmul(e0,m01), u10 = cmul(e1,m10), u11 = cmul(e1,m11);
      float* o = sg + g*8;
      o[0]=u00.r; o[1]=u00.i; o[2]=u01.r; o[3]=u01.i;
      o[4]=u10.r; o[5]=u10.i; o[6]=u11.r; o[7]=u11.i;
    }
    __syncthreads();
    int lane = tid & 63;
    int wid = blk*4 + (tid >> 6);
    int bcol = wid & 255;
    int p = __popc(bcol) & 3;
    float phr = (p==0) ? 1.f : ((p==2) ? -1.f : 0.f);
    float phi = (p==1) ? -1.f : ((p==3) ? 1.f : 0.f);
    float re[4], im[4];
    #pragma unroll
    for (int j = 0; j < 4; ++j) {
      int idx = 4*lane + j;
      re[j] = (idx==bcol) ? phr : 0.f;
      im[j] = (idx==bcol) ? phi : 0.f;
    }
    #pragma unroll
    for (int l = 0; l < 3; ++l) {
      #pragma unroll
      for (int q = 0; q < 8; ++q) {
        const float* u = &sg[(size_t)(l*8 + q)*8];
        float u00r=u[0],u00i=u[1],u01r=u[2],u01i=u[3];
        float u10r=u[4],u10i=u[5],u11r=u[6],u11i=u[7];
        if (q < 6) {
          int m = 5-q, mask = 1<<m;
          bool s1 = ((lane >> m) & 1) != 0;
          float udr = s1?u11r:u00r, udi = s1?u11i:u00i;
          float uor = s1?u10r:u01r, uoi = s1?u10i:u01i;
          #pragma unroll
          for (int j = 0; j < 4; ++j) {
            float pr = __shfl_xor(re[j], mask);
            float pi = __shfl_xor(im[j], mask);
            float nr = udr*re[j] - udi*im[j] + uor*pr - uoi*pi;
            float ni = udr*im[j] + udi*re[j] + uor*pi + uoi*pr;
            re[j]=nr; im[j]=ni;
          }
        } else if (q == 6) { APPLY2(0,2); APPLY2(1,3); }
        else               { APPLY2(0,1); APPLY2(2,3); }
      }
      #pragma unroll
      for (int cq = 0; cq <= 4; ++cq) {
        int tmask = 1 << (4-cq);
        bool pred = ((lane >> (5-cq)) & 1) != 0;
        #pragma unroll
        for (int j = 0; j < 4; ++j) {
          float sr = __shfl_xor(re[j], tmask);
          float si = __shfl_xor(im[j], tmask);
          re[j] = pred ? sr : re[j];
          im[j] = pred ? si : im[j];
        }
      }
      { bool pred = (lane & 1) != 0;
        float t0, t1;
        t0 = pred?re[2]:re[0]; t1 = pred?re[0]:re[2]; re[0]=t0; re[2]=t1;
        t0 = pred?im[2]:im[0]; t1 = pred?im[0]:im[2]; im[0]=t0; im[2]=t1;
        t0 = pred?re[3]:re[1]; t1 = pred?re[1]:re[3]; re[1]=t0; re[3]=t1;
        t0 = pred?im[3]:im[1]; t1 = pred?im[1]:im[3]; im[1]=t0; im[3]=t1; }
      { float t;
        t=re[2]; re[2]=re[3]; re[3]=t;
        t=im[2]; im[2]=im[3]; im[3]=t; }
      { re[1]=__shfl_xor(re[1],32); im[1]=__shfl_xor(im[1],32);
        re[3]=__shfl_xor(re[3],32); im[3]=__shfl_xor(im[3],32); }
    }
    #pragma unroll
    for (int j = 0; j < 4; ++j) {
      int i = 4*lane + j;
      Bm[(size_t)(c*512 + i)*256 + bcol]       = f2bf(re[j]);
      Bm[(size_t)(c*512 + 256 + i)*256 + bcol] = f2bf(im[j]);
    }
  } else if (blk < 192) {
    // ---- w1pack ----
    int slot = (blk-128)*256 + tid;
    int n = slot & 255, h5 = (slot>>8)&1, ks = (slot>>9)&7, p = (slot>>12)&1, c = slot>>13;
    const float* w1c = c ? w1b : w1a;
    #pragma unroll
    for (int j = 0; j < 8; ++j) {
      float v = w1c[(size_t)(ks*16 + h5*8 + j)*256 + n];
      unsigned short hi = f2bf(v);
      w1p[(size_t)slot*8 + j] = p ? f2bf(v - bf2f(hi)) : hi;
    }
  } else if (blk < 200) {
    // ---- w2pack ----
    int slot = (blk-192)*256 + tid;
    int combo = slot >> 4, part = slot & 15;
    int h5 = combo&1, k16 = (combo>>1)&15, p = (combo>>5)&1, c = (combo>>6)&1;
    const float* w2c = c ? w2b : w2a;
    #pragma unroll
    for (int jj = 0; jj < 16; ++jj) {
      int idx = part*16 + jj;
      int il = idx >> 3, j = idx & 7;
      int n = k16*16 + h5*8 + j;
      float v = (il < 8) ? w2c[(size_t)n*8 + il] : 0.f;
      unsigned short hi = f2bf(v);
      w2p[(size_t)combo*256 + idx] = p ? f2bf(v - bf2f(hi)) : hi;
    }
  } else {
    // ---- Gm2: A-frags for rank-8 stage2 (|w4|-scaled, b3s in k=8 row).
    // Gm[((c*8+w)*64+lane)*8+j]:
    //   h5=0        -> bf16(w3[j][n] * |w4[n]|)     (k = j, rows 0..7)
    //   h5=1, j==0  -> bf16(b3[n] * |w4[n]|)        (k = 8 bias row)
    //   else        -> 0
    int idx = (blk-200)*256 + tid;          // [0, 8192)
    int j = idx & 7, lane = (idx >> 3) & 63, w = (idx >> 9) & 7, c = (idx >> 12) & 1;
    int h5 = lane >> 5, il = lane & 31;
    int n = 32*w + il;
    const float* w3 = c ? w3b : w3a;
    const float* w4 = c ? w4b : w4a;
    const float* b3 = c ? b3b : b3a;
    float aw = fabsf(w4[n]);
    float v;
    if (h5 == 0)     v = w3[(size_t)j*256 + n] * aw;
    else if (j == 0) v = b3[n] * aw;
    else             v = 0.f;
    Gm[idx] = f2bf(v);
  }
}

// ---------------------------------------------------------------------------
// enc_mfma: unchanged from R9 (32 rows/block, 4 waves/SIMD).
// ---------------------------------------------------------------------------
__global__ __launch_bounds__(256, 4)
void enc_mfma(const float* __restrict__ state, const float* __restrict__ action,
              const unsigned short* __restrict__ w1p,
              const float* __restrict__ b1a, const float* __restrict__ b1b,
              const unsigned short* __restrict__ w2p,
              const float* __restrict__ b2a, const float* __restrict__ b2b,
              float* __restrict__ enc, int Bn) {
  __shared__ __align__(16) char Bx[2][8192];
  __shared__ __align__(16) float sb1[2][256];
  __shared__ float sb2[2][8];
  __shared__ __align__(16) float encw[4][32][8];
  int tid = threadIdx.x;
  int lane = tid & 63, w = tid >> 6, il = lane & 31, h5 = lane >> 5;
  int r0 = blockIdx.x * 32;

  sb1[0][tid] = b1a[tid];
  sb1[1][tid] = b1b[tid];
  if (tid < 8) { sb2[0][tid] = b2a[tid]; sb2[1][tid] = b2b[tid]; }

  {
    int m = tid >> 3, q8 = tid & 7;
    const float4* st4 = (const float4*)state;
    const float4* ac4 = (const float4*)action;
    #pragma unroll
    for (int j = 0; j < 4; ++j) {
      int f = j*8 + q8;                 // float4 slot 0..31 of the row
      int ks = f >> 2, kq = f & 3;
      float4 v = (ks < 6) ? st4[(size_t)(r0+m)*24 + ks*4 + kq]
                          : ac4[(size_t)(r0+m)*8 + (ks-6)*4 + kq];
      unsigned short hx = f2bf(v.x), hy = f2bf(v.y), hz = f2bf(v.z), hw = f2bf(v.w);
      uint2 hh, ll;
      hh.x = (unsigned)hx | ((unsigned)hy << 16);
      hh.y = (unsigned)hz | ((unsigned)hw << 16);
      ll.x = (unsigned)f2bf(v.x - bf2f(hx)) | ((unsigned)f2bf(v.y - bf2f(hy)) << 16);
      ll.y = (unsigned)f2bf(v.z - bf2f(hz)) | ((unsigned)f2bf(v.w - bf2f(hw)) << 16);
      int off = ks*1024 + m*32 + kq*8;
      *(uint2*)(&Bx[0][off]) = hh;
      *(uint2*)(&Bx[1][off]) = ll;
    }
  }
  __syncthreads();

  for (int c = 0; c < 2; ++c) {
    accv_t A[2] = {{},{}};
    #pragma unroll
    for (int ks = 0; ks < 8; ++ks) {
      bfrag_t a0h, a0l, a1h, a1l;
      {
        size_t b0 = ((size_t)((c*2+0)*8 + ks)*2 + h5)*256;
        size_t b1 = ((size_t)((c*2+1)*8 + ks)*2 + h5)*256;
        int t0 = 2*w, t1 = 2*w+1;
        a0h = *(const bfrag_t*)(w1p + (b0 + t0*32 + il)*8);
        a0l = *(const bfrag_t*)(w1p + (b1 + t0*32 + il)*8);
        a1h = *(const bfrag_t*)(w1p + (b0 + t1*32 + il)*8);
        a1l = *(const bfrag_t*)(w1p + (b1 + t1*32 + il)*8);
      }
      bfrag_t b0h = *(const bfrag_t*)(&Bx[0][ks*1024 + il*32 + h5*16]);
      bfrag_t b0l = *(const bfrag_t*)(&Bx[1][ks*1024 + il*32 + h5*16]);
      A[0] = __builtin_amdgcn_mfma_f32_32x32x16_bf16(a0h, b0h, A[0], 0,0,0);
      A[0] = __builtin_amdgcn_mfma_f32_32x32x16_bf16(a0h, b0l, A[0], 0,0,0);
      A[0] = __builtin_amdgcn_mfma_f32_32x32x16_bf16(a0l, b0h, A[0], 0,0,0);
      A[1] = __builtin_amdgcn_mfma_f32_32x32x16_bf16(a1h, b0h, A[1], 0,0,0);
      A[1] = __builtin_amdgcn_mfma_f32_32x32x16_bf16(a1h, b0l, A[1], 0,0,0);
      A[1] = __builtin_amdgcn_mfma_f32_32x32x16_bf16(a1l, b0h, A[1], 0,0,0);
    }
    #pragma unroll
    for (int nt = 0; nt < 2; ++nt) {
      #pragma unroll
      for (int g = 0; g < 4; ++g) {
        float4 bb = *(const float4*)&sb1[c][(2*w+nt)*32 + 8*g + 4*h5];
        float bba[4] = {bb.x, bb.y, bb.z, bb.w};
        #pragma unroll
        for (int jj = 0; jj < 4; ++jj) {
          A[nt][4*g+jj] = fmaxf(A[nt][4*g+jj] + bba[jj], 0.f);
        }
      }
    }
    accv_t Cm = {};
    #pragma unroll
    for (int k2 = 0; k2 < 4; ++k2) {
      int k16 = 4*w + k2;
      bfrag_t g2h = *(const bfrag_t*)(w2p + ((size_t)((c*2+0)*16 + k16)*2 + h5)*256 + il*8);
      bfrag_t g2l = *(const bfrag_t*)(w2p + ((size_t)((c*2+1)*16 + k16)*2 + h5)*256 + il*8);
      unsigned ph[2][2], pl[2][2];
      #pragma unroll
      for (int gi = 0; gi < 2; ++gi) {
        int G = 2*k2 + gi, nt = G >> 2, g = G & 3;
        float f0 = A[nt][4*g+0], f1 = A[nt][4*g+1];
        float f2 = A[nt][4*g+2], f3 = A[nt][4*g+3];
        unsigned short h0 = f2bf(f0), h1 = f2bf(f1), h2 = f2bf(f2), h3 = f2bf(f3);
        ph[gi][0] = (unsigned)h0 | ((unsigned)h1 << 16);
        ph[gi][1] = (unsigned)h2 | ((unsigned)h3 << 16);
        pl[gi][0] = (unsigned)f2bf(f0 - bf2f(h0)) | ((unsigned)f2bf(f1 - bf2f(h1)) << 16);
        pl[gi][1] = (unsigned)f2bf(f2 - bf2f(h2)) | ((unsigned)f2bf(f3 - bf2f(h3)) << 16);
      }
      union { bfrag_t v; unsigned u[4]; } FH, FL;
      #pragma unroll
      for (int r = 0; r < 2; ++r) {
        unsigned own_h = h5 ? ph[1][r] : ph[0][r];
        unsigned alt_h = h5 ? ph[0][r] : ph[1][r];
        unsigned rec_h = __shfl_xor((int)alt_h, 32);
        FH.u[r]   = h5 ? rec_h : own_h;
        FH.u[2+r] = h5 ? own_h : rec_h;
        unsigned own_l = h5 ? pl[1][r] : pl[0][r];
        unsigned alt_l = h5 ? pl[0][r] : pl[1][r];
        unsigned rec_l = __shfl_xor((int)alt_l, 32);
        FL.u[r]   = h5 ? rec_l : own_l;
        FL.u[2+r] = h5 ? own_l : rec_l;
      }
      Cm = __builtin_amdgcn_mfma_f32_32x32x16_bf16(g2h, FH.v, Cm, 0,0,0);
      Cm = __builtin_amdgcn_mfma_f32_32x32x16_bf16(g2h, FL.v, Cm, 0,0,0);
      Cm = __builtin_amdgcn_mfma_f32_32x32x16_bf16(g2l, FH.v, Cm, 0,0,0);
    }
    *(float4*)&encw[w][il][4*h5] = make_float4(Cm[0], Cm[1], Cm[2], Cm[3]);
    __syncthreads();
    {
      int e = tid & 7, mm = tid >> 3;
      float v = sb2[c][e];
      #pragma unroll
      for (int ww = 0; ww < 4; ++ww) v += encw[ww][mm][e];
      enc[((size_t)c*Bn + r0 + mm)*8 + e] = v;
    }
    __syncthreads();
  }
}

// ---------------------------------------------------------------------------
// qgemm R12 helpers
// ---------------------------------------------------------------------------
__device__ __forceinline__ void a_build(float4 ea, float4 eb, char* Ab, int ag2, int am) {
  float c0,s0,c1,s1,c2,s2,c3,s3,c4,s4,c5,s5,c6,s6,c7,s7;
  __sincosf(0.5f*ea.x, &s0, &c0);
  __sincosf(0.5f*ea.y, &s1, &c1);
  __sincosf(0.5f*ea.z, &s2, &c2);
  __sincosf(0.5f*ea.w, &s3, &c3);
  __sincosf(0.5f*eb.x, &s4, &c4);
  __sincosf(0.5f*eb.y, &s5, &c5);
  __sincosf(0.5f*eb.z, &s6, &c6);
  __sincosf(0.5f*eb.w, &s7, &c7);
  float v0 = (ag2&8) ? s0 : c0;
  float v1 = (ag2&4) ? s1 : c1;
  float v2 = (ag2&2) ? s2 : c2;
  float v3 = (ag2&1) ? s3 : c3;
  float top = v0*v1*v2*v3;
  float hA = top*c4, hB = top*s4;
  float p67[4];
  p67[0] = c6*c7; p67[1] = c6*s7; p67[2] = s6*c7; p67[3] = s6*s7;
  float low[8];
  #pragma unroll
  for (int j = 0; j < 8; ++j) low[j] = ((j&4) ? s5 : c5) * p67[j&3];
  union { bfrag_t v; unsigned u[4]; } pk;
  #pragma unroll
  for (int k = 0; k < 4; ++k) pk.u[k] = pack2(hA*low[2*k], hA*low[2*k+1]);
  *(bfrag_t*)(Ab + ag2*1024 + am*16) = pk.v;
  #pragma unroll
  for (int k = 0; k < 4; ++k) pk.u[k] = pack2(hB*low[2*k], hB*low[2*k+1]);
  *(bfrag_t*)(Ab + ag2*1024 + 512 + am*16) = pk.v;
}

// ---------------------------------------------------------------------------
// qgemm R12: 512 thr = 8 waves, grid 256, 8 iters of 64 rows.
// Per iter: S1 both subtiles (swapped MFMA, ex bit-sign partials -> exw) |
// B2 | deferred out-reduce(prev iter) + exw->exf + A-build(next) | B3 |
// S2 swapped (lane=m, r=n; bias in k=8 row) + per-lane n-sum + qp write.
// 2 barriers/iter. LDS 56.6KB.
// ---------------------------------------------------------------------------
__global__ __launch_bounds__(512, 2)
void qgemm(const float* __restrict__ enc,
           const unsigned short* __restrict__ Bm, const unsigned short* __restrict__ Gm,
           const float* __restrict__ b3a, const float* __restrict__ w4a, const float* __restrict__ b4a,
           const float* __restrict__ b3b, const float* __restrict__ w4b, const float* __restrict__ b4b,
           float* __restrict__ out, int Bn) {
  __shared__ __align__(16) char APq[56576];
  char* A0 = APq;                        // [g2*1024 + half*512 + m*16]
  char* A1 = APq + 16384;
  float* exw = (float*)(APq + 32768);    // [sub*2304 + w*288 + m*9 + q] f32
  float* exf = (float*)(APq + 51200);    // [sub*384 + m*12 + q] f32
  float* qp  = (float*)(APq + 54272);    // [row*9 + w] f32 (64x9)

  int tid = threadIdx.x;
  int lane = tid & 63;
  int w = tid >> 6;
  int il = lane & 31;
  int h5 = lane >> 5;

  int c = blockIdx.x >> 7;
  int rowblock = blockIdx.x & 127;
  int rowsPerBlock = Bn >> 7;        // 512
  int npairs = rowsPerBlock >> 6;    // 8

  // ---- persistent W-frags: tile pair (w, 8+w), 128 regs ----
  bfrag_t bf0[16], bf1[16];
  {
    const unsigned short* base = Bm + ((size_t)(c*512 + 32*w + il)*256 + h5*8);
    #pragma unroll
    for (int ks = 0; ks < 16; ++ks) {
      bf0[ks] = *(const bfrag_t*)(base + ks*16);
      bf1[ks] = *(const bfrag_t*)(base + 256*256 + ks*16);
    }
  }
  // resident w3s/b3s A-frag (4 VGPRs)
  bfrag_t gf2 = *(const bfrag_t*)(Gm + ((size_t)((c*8 + w)*64 + lane))*8);

  int n2 = 32*w + il;
  const float* w4c = c ? w4b : w4a;
  const float* b4c = c ? b4b : b4a;
  float w4v = w4c[n2];
  float b4v = b4c[0];
  // sign mask for the wave's 32-col w4 slice (bits = il, duplicated 32-63)
  unsigned smask = (unsigned)__ballot(w4v < 0.f);

  int am = tid & 31, ag2 = tid >> 5;
  const float* encb = enc + ((size_t)c*Bn)*8;
  int rbase = rowblock*rowsPerBlock;

  // ---- prologue: A-build for first 64 rows ----
  {
    const float* ep0 = encb + (size_t)(rbase + am)*8;
    float4 pa0 = *(const float4*)ep0, pb0 = *(const float4*)(ep0 + 4);
    const float* ep1 = encb + (size_t)(rbase + 32 + am)*8;
    float4 pa1 = *(const float4*)ep1, pb1 = *(const float4*)(ep1 + 4);
    a_build(pa0, pb0, A0, ag2, am);
    a_build(pa1, pb1, A1, ag2, am);
  }
  __syncthreads();

  for (int st2 = 0; st2 < npairs; ++st2) {
    int r0 = rbase + st2*64;
    // ===== phase1: stage1 both subtiles, swapped operands; ex partials =====
    #pragma unroll
    for (int sub = 0; sub < 2; ++sub) {
      const char* Asel = sub ? A1 : A0;
      accv_t acc0 = {}, acc1 = {};
      #pragma unroll
      for (int ks = 0; ks < 16; ++ks) {
        bfrag_t af = *(const bfrag_t*)(Asel + ks*1024 + lane*16);
        acc0 = __builtin_amdgcn_mfma_f32_32x32x16_bf16(bf0[ks], af, acc0, 0, 0, 0);
        acc1 = __builtin_amdgcn_mfma_f32_32x32x16_bf16(bf1[ks], af, acc1, 0, 0, 0);
      }
      // lane holds P[i_local(r,h5)][m=il]; i bits: 0-1=r&3, 2=h5, 3-4=r>>2
      float Pv[16];
      #pragma unroll
      for (int r = 0; r < 16; ++r) Pv[r] = acc0[r]*acc0[r] + acc1[r]*acc1[r];
      float E  = ((Pv[0]+Pv[1])+(Pv[2]+Pv[3])) + ((Pv[4]+Pv[5])+(Pv[6]+Pv[7]));
      float S4 = ((Pv[8]+Pv[9])+(Pv[10]+Pv[11])) + ((Pv[12]+Pv[13])+(Pv[14]+Pv[15]));
      float T  = E + S4;
      float S0 = ((Pv[1]+Pv[3])+(Pv[5]+Pv[7])) + ((Pv[9]+Pv[11])+(Pv[13]+Pv[15]));
      float S1 = ((Pv[2]+Pv[3])+(Pv[6]+Pv[7])) + ((Pv[10]+Pv[11])+(Pv[14]+Pv[15]));
      float S3 = ((Pv[4]+Pv[5])+(Pv[6]+Pv[7])) + ((Pv[12]+Pv[13])+(Pv[14]+Pv[15]));
      float e[8];
      e[7] = T - 2.f*S0;           // q=7 <- i bit0
      e[6] = T - 2.f*S1;           // bit1
      e[5] = h5 ? -T : T;          // bit2 = h5
      e[4] = T - 2.f*S3;           // bit3
      e[3] = T - 2.f*S4;           // bit4
      e[2] = (w&1) ? -T : T;       // bit5
      e[1] = (w&2) ? -T : T;       // bit6
      e[0] = (w&4) ? -T : T;       // bit7
      #pragma unroll
      for (int q = 0; q < 8; ++q) e[q] += __shfl_xor(e[q], 32);
      if (h5 == 0) {
        float* dst = exw + sub*2304 + w*288 + il*9;
        #pragma unroll
        for (int q = 0; q < 8; ++q) dst[q] = e[q];
      }
    }
    __syncthreads();                                   // B2: exw ready, A reads done
    // ===== phase2: deferred out-write(prev) + exw->exf + A-build(next) =====
    if (st2 > 0 && tid < 64) {
      const float* qr = qp + tid*9;
      float s = ((qr[0]+qr[1]) + (qr[2]+qr[3])) + ((qr[4]+qr[5]) + (qr[6]+qr[7]));
      out[(size_t)c*Bn + (r0 - 64) + tid] = s + b4v;
    }
    float4 na0, nb0, na1, nb1;
    bool more = (st2 + 1 < npairs);
    if (more) {
      const float* ep0 = encb + (size_t)(r0 + 64 + am)*8;
      na0 = *(const float4*)ep0; nb0 = *(const float4*)(ep0 + 4);
      const float* ep1 = encb + (size_t)(r0 + 96 + am)*8;
      na1 = *(const float4*)ep1; nb1 = *(const float4*)(ep1 + 4);
    }
    {
      int sub = tid >> 8, m = (tid >> 3) & 31, q = tid & 7;
      const float* ew = exw + sub*2304 + m*9 + q;
      float s = ((ew[0] + ew[288]) + (ew[2*288] + ew[3*288]))
              + ((ew[4*288] + ew[5*288]) + (ew[6*288] + ew[7*288]));
      exf[sub*384 + m*12 + q] = s;
    }
    if (more) {
      a_build(na0, nb0, A0, ag2, am);
      a_build(na1, nb1, A1, ag2, am);
    }
    __syncthreads();                                   // B3: exf + next-A ready
    // ===== phase3: stage2 swapped (lane=m, r=n) + per-lane n-sum + qp =====
    {
      union { bfrag_t v; unsigned u[4]; } fa, fb;
      if (h5 == 0) {
        const float* e0 = exf + il*12;
        float4 x0 = *(const float4*)(e0);
        float4 x1 = *(const float4*)(e0 + 4);
        fa.u[0] = pack2(x0.x, x0.y); fa.u[1] = pack2(x0.z, x0.w);
        fa.u[2] = pack2(x1.x, x1.y); fa.u[3] = pack2(x1.z, x1.w);
        const float* e1 = exf + 384 + il*12;
        float4 y0 = *(const float4*)(e1);
        float4 y1 = *(const float4*)(e1 + 4);
        fb.u[0] = pack2(y0.x, y0.y); fb.u[1] = pack2(y0.z, y0.w);
        fb.u[2] = pack2(y1.x, y1.y); fb.u[3] = pack2(y1.z, y1.w);
      } else {
        // k=8 bias row: constant 1.0 multiplies Gm2's b3s row
        fa.u[0] = 0x00003F80u; fa.u[1]=0; fa.u[2]=0; fa.u[3]=0;
        fb.u[0] = 0x00003F80u; fb.u[1]=0; fb.u[2]=0; fb.u[3]=0;
      }
      accv_t acc2a = {}, acc2b = {};
      acc2a = __builtin_amdgcn_mfma_f32_32x32x16_bf16(gf2, fa.v, acc2a, 0, 0, 0);
      acc2b = __builtin_amdgcn_mfma_f32_32x32x16_bf16(gf2, fb.v, acc2b, 0, 0, 0);
      // lane = batch m (=il); r = n_local = (r&3)+8*(r>>2)+4*h5 in wave slice
      float qa = 0.f, qb = 0.f;
      #pragma unroll
      for (int r = 0; r < 16; ++r) {
        int bi = (r&3) + 8*(r>>2);
        float ta = fmaxf(acc2a[r], 0.f);
        float tb = fmaxf(acc2b[r], 0.f);
        bool neg = ((smask >> (bi + 4*h5)) & 1u) != 0u;
        qa += neg ? -ta : ta;
        qb += neg ? -tb : tb;
      }
      qa += __shfl_xor(qa, 32);
      qb += __shfl_xor(qb, 32);
      if (h5 == 0) {
        qp[il*9 + w]        = qa;
        qp[(32 + il)*9 + w] = qb;
      }
    }
    // no barrier: next phase1 writes exw (last read pre-B3), reads A
    // (built phase2, post-B3); qp read is after next B2.
  }
  // ---- epilogue: out-write for the last iteration ----
  __syncthreads();
  if (tid < 64) {
    const float* qr = qp + tid*9;
    float s = ((qr[0]+qr[1]) + (qr[2]+qr[3])) + ((qr[4]+qr[5]) + (qr[6]+qr[7]));
    out[(size_t)c*Bn + rbase + (npairs-1)*64 + tid] = s + b4v;
  }
}

extern "C" void kernel_launch(void* const* d_in, const int* in_sizes, int n_in,
                              void* d_out, int out_size, void* d_ws, size_t ws_size,
                              hipStream_t stream) {
  (void)n_in; (void)out_size; (void)ws_size;
  const float* state  = (const float*)d_in[0];
  const float* action = (const float*)d_in[1];
  const float* w1a=(const float*)d_in[2];  const float* b1a=(const float*)d_in[3];
  const float* w2a=(const float*)d_in[4];  const float* b2a=(const float*)d_in[5];
  const float* qrxa=(const float*)d_in[6]; const float* qrya=(const float*)d_in[7];
  const float* qrza=(const float*)d_in[8];
  const float* w3a=(const float*)d_in[9];  const float* b3a=(const float*)d_in[10];
  const float* w4a=(const float*)d_in[11]; const float* b4a=(const float*)d_in[12];
  const float* w1b=(const float*)d_in[13]; const float* b1b=(const float*)d_in[14];
  const float* w2b=(const float*)d_in[15]; const float* b2b=(const float*)d_in[16];
  const float* qrxb=(const float*)d_in[17];const float* qryb=(const float*)d_in[18];
  const float* qrzb=(const float*)d_in[19];
  const float* w3b=(const float*)d_in[20]; const float* b3b=(const float*)d_in[21];
  const float* w4b=(const float*)d_in[22]; const float* b4b=(const float*)d_in[23];

  int B = in_sizes[0] / 96;
  char* wsb = (char*)d_ws;
  unsigned short* Bmat = (unsigned short*)(wsb);                 // 524288 B
  unsigned short* Gmat = (unsigned short*)(wsb + 524288);        // 16384 B used
  unsigned short* w1p  = (unsigned short*)(wsb + 786432);        // 262144 B
  unsigned short* w2p  = (unsigned short*)(wsb + 1048576);       // 65536 B
  float* enc           = (float*)(wsb + 1114112);                // 2*B*8*4 B

  prep_weights<<<232, 256, 0, stream>>>(qrxa,qrya,qrza,qrxb,qryb,qrzb,
                                        w1a,w1b,w2a,w2b,w3a,w3b,w4a,w4b,b3a,b3b,
                                        Bmat,Gmat,w1p,w2p);
  enc_mfma<<<B/32, 256, 0, stream>>>(state,action,w1p,b1a,b1b,w2p,b2a,b2b,enc,B);
  qgemm<<<256, 512, 0, stream>>>(enc, Bmat, Gmat, b3a, w4a, b4a, b3b, w4b, b4b,
                                 (float*)d_out, B);
}

// Round 10
// 198.561 us; speedup vs baseline: 1.2098x; 1.0222x over previous
//
#include <hip/hip_runtime.h>
#include <math.h>

// ---------------------------------------------------------------------------
// QuantumCritic R13.
//   psi = W r ; P = |psi|^2 ; ex[q] = sum_i sign(i,q) P[i] (rank-8)
//   q = sum_n sign(w4[n]) * relu(ex.(w3[:,n]|w4[n]|) + b3[n]|w4[n]|) + b4
// R13 changes vs R12 (post-mortem: MFMA floor 13.7us reached 26%; remaining =
// VALU 17 + DS 13 + barriers/bubbles 9. Consolidation: fewer barriers, dedup
// redundant packing):
//   - qgemm 128 rows/iter (4 subs), 4 iters: barriers 16 -> 8. LDS 111KB
//     (A 64K | exw 36.9K | exf 4K | qp 4.6K). Subs sequential -> regs flat.
//   - exf stored PRE-PACKED bf16 (u32 pairs) by phase2 (one pack2 per
//     thread) — was 16 pack2 per thread x8 waves redundantly in phase3.
//     Phase3 fa = single b128 read.
//   - enc prefetch regs dropped: enc is L2-resident (~200cy), loaded at
//     phase2 start, hidden under exf reduce.
// ---------------------------------------------------------------------------

typedef __attribute__((ext_vector_type(8))) short bfrag_t;   // 8 bf16 = 4 VGPR
typedef __attribute__((ext_vector_type(16))) float accv_t;   // 32x32 MFMA acc

__device__ __forceinline__ unsigned short f2bf(float x) {
  unsigned u = __float_as_uint(x);
  u += 0x7FFFu + ((u >> 16) & 1u);      // RNE
  return (unsigned short)(u >> 16);
}
__device__ __forceinline__ float bf2f(unsigned short h) {
  return __uint_as_float(((unsigned)h) << 16);
}
__device__ __forceinline__ unsigned pack2(float a, float b) {
  return (unsigned)f2bf(a) | ((unsigned)f2bf(b) << 16);
}

struct C2 { float r, i; };
__device__ __forceinline__ C2 cmul(C2 a, C2 b){ return C2{a.r*b.r - a.i*b.i, a.r*b.i + a.i*b.r}; }
__device__ __forceinline__ C2 cadd(C2 a, C2 b){ return C2{a.r+b.r, a.i+b.i}; }

#define APPLY2(A,Bx)                                                        \
  { float ar=re[A], ai=im[A], br=re[Bx], bi=im[Bx];                         \
    re[A]  = u00r*ar - u00i*ai + u01r*br - u01i*bi;                         \
    im[A]  = u00r*ai + u00i*ar + u01r*bi + u01i*br;                         \
    re[Bx] = u10r*ar - u10i*ai + u11r*br - u11i*bi;                         \
    im[Bx] = u10r*ai + u10i*ar + u11r*bi + u11i*br; }

__global__ __launch_bounds__(256)
void prep_weights(const float* __restrict__ qrxa, const float* __restrict__ qrya,
                  const float* __restrict__ qrza,
                  const float* __restrict__ qrxb, const float* __restrict__ qryb,
                  const float* __restrict__ qrzb,
                  const float* __restrict__ w1a, const float* __restrict__ w1b,
                  const float* __restrict__ w2a, const float* __restrict__ w2b,
                  const float* __restrict__ w3a, const float* __restrict__ w3b,
                  const float* __restrict__ w4a, const float* __restrict__ w4b,
                  const float* __restrict__ b3a, const float* __restrict__ b3b,
                  unsigned short* __restrict__ Bm, unsigned short* __restrict__ Gm,
                  unsigned short* __restrict__ w1p, unsigned short* __restrict__ w2p) {
  int blk = blockIdx.x;
  int tid = threadIdx.x;
  if (blk < 128) {
    // ---- prep_W: circuit on 256 basis columns ----
    __shared__ float sg[192];
    int c = blk >> 6;
    if (tid < 24) {
      const float* qx = c ? qrxb : qrxa;
      const float* qy = c ? qryb : qrya;
      const float* qz = c ? qrzb : qrza;
      int g = tid;
      float tx = 0.5f*qx[g], ty = 0.5f*qy[g], tz = 0.5f*qz[g];
      float cx = cosf(tx), sx = sinf(tx);
      float cy = cosf(ty), sy = sinf(ty);
      float cz = cosf(tz), sz = sinf(tz);
      C2 rx00{cx,0.f}, rx01{0.f,-sx}, rx10{0.f,-sx}, rx11{cx,0.f};
      C2 m00 = cadd(cmul(C2{cy,0.f},rx00), cmul(C2{-sy,0.f},rx10));
      C2 m01 = cadd(cmul(C2{cy,0.f},rx01), cmul(C2{-sy,0.f},rx11));
      C2 m10 = cadd(cmul(C2{sy,0.f},rx00), cmul(C2{cy,0.f},rx10));
      C2 m11 = cadd(cmul(C2{sy,0.f},rx01), cmul(C2{cy,0.f},rx11));
      C2 e0{cz,-sz}, e1{cz,sz};
      C2 u00 = cmul(e0,m00), u01 = cmul(e0,m01), u10 = cmul(e1,m10), u11 = cmul(e1,m11);
      float* o = sg + g*8;
      o[0]=u00.r; o[1]=u00.i; o[2]=u01.r; o[3]=u01.i;
      o[4]=u10.r; o[5]=u10.i; o[6]=u11.r; o[7]=u11.i;
    }
    __syncthreads();
    int lane = tid & 63;
    int wid = blk*4 + (tid >> 6);
    int bcol = wid & 255;
    int p = __popc(bcol) & 3;
    float phr = (p==0) ? 1.f : ((p==2) ? -1.f : 0.f);
    float phi = (p==1) ? -1.f : ((p==3) ? 1.f : 0.f);
    float re[4], im[4];
    #pragma unroll
    for (int j = 0; j < 4; ++j) {
      int idx = 4*lane + j;
      re[j] = (idx==bcol) ? phr : 0.f;
      im[j] = (idx==bcol) ? phi : 0.f;
    }
    #pragma unroll
    for (int l = 0; l < 3; ++l) {
      #pragma unroll
      for (int q = 0; q < 8; ++q) {
        const float* u = &sg[(size_t)(l*8 + q)*8];
        float u00r=u[0],u00i=u[1],u01r=u[2],u01i=u[3];
        float u10r=u[4],u10i=u[5],u11r=u[6],u11i=u[7];
        if (q < 6) {
          int m = 5-q, mask = 1<<m;
          bool s1 = ((lane >> m) & 1) != 0;
          float udr = s1?u11r:u00r, udi = s1?u11i:u00i;
          float uor = s1?u10r:u01r, uoi = s1?u10i:u01i;
          #pragma unroll
          for (int j = 0; j < 4; ++j) {
            float pr = __shfl_xor(re[j], mask);
            float pi = __shfl_xor(im[j], mask);
            float nr = udr*re[j] - udi*im[j] + uor*pr - uoi*pi;
            float ni = udr*im[j] + udi*re[j] + uor*pi + uoi*pr;
            re[j]=nr; im[j]=ni;
          }
        } else if (q == 6) { APPLY2(0,2); APPLY2(1,3); }
        else               { APPLY2(0,1); APPLY2(2,3); }
      }
      #pragma unroll
      for (int cq = 0; cq <= 4; ++cq) {
        int tmask = 1 << (4-cq);
        bool pred = ((lane >> (5-cq)) & 1) != 0;
        #pragma unroll
        for (int j = 0; j < 4; ++j) {
          float sr = __shfl_xor(re[j], tmask);
          float si = __shfl_xor(im[j], tmask);
          re[j] = pred ? sr : re[j];
          im[j] = pred ? si : im[j];
        }
      }
      { bool pred = (lane & 1) != 0;
        float t0, t1;
        t0 = pred?re[2]:re[0]; t1 = pred?re[0]:re[2]; re[0]=t0; re[2]=t1;
        t0 = pred?im[2]:im[0]; t1 = pred?im[0]:im[2]; im[0]=t0; im[2]=t1;
        t0 = pred?re[3]:re[1]; t1 = pred?re[1]:re[3]; re[1]=t0; re[3]=t1;
        t0 = pred?im[3]:im[1]; t1 = pred?im[1]:im[3]; im[1]=t0; im[3]=t1; }
      { float t;
        t=re[2]; re[2]=re[3]; re[3]=t;
        t=im[2]; im[2]=im[3]; im[3]=t; }
      { re[1]=__shfl_xor(re[1],32); im[1]=__shfl_xor(im[1],32);
        re[3]=__shfl_xor(re[3],32); im[3]=__shfl_xor(im[3],32); }
    }
    #pragma unroll
    for (int j = 0; j < 4; ++j) {
      int i = 4*lane + j;
      Bm[(size_t)(c*512 + i)*256 + bcol]       = f2bf(re[j]);
      Bm[(size_t)(c*512 + 256 + i)*256 + bcol] = f2bf(im[j]);
    }
  } else if (blk < 192) {
    // ---- w1pack ----
    int slot = (blk-128)*256 + tid;
    int n = slot & 255, h5 = (slot>>8)&1, ks = (slot>>9)&7, p = (slot>>12)&1, c = slot>>13;
    const float* w1c = c ? w1b : w1a;
    #pragma unroll
    for (int j = 0; j < 8; ++j) {
      float v = w1c[(size_t)(ks*16 + h5*8 + j)*256 + n];
      unsigned short hi = f2bf(v);
      w1p[(size_t)slot*8 + j] = p ? f2bf(v - bf2f(hi)) : hi;
    }
  } else if (blk < 200) {
    // ---- w2pack ----
    int slot = (blk-192)*256 + tid;
    int combo = slot >> 4, part = slot & 15;
    int h5 = combo&1, k16 = (combo>>1)&15, p = (combo>>5)&1, c = (combo>>6)&1;
    const float* w2c = c ? w2b : w2a;
    #pragma unroll
    for (int jj = 0; jj < 16; ++jj) {
      int idx = part*16 + jj;
      int il = idx >> 3, j = idx & 7;
      int n = k16*16 + h5*8 + j;
      float v = (il < 8) ? w2c[(size_t)n*8 + il] : 0.f;
      unsigned short hi = f2bf(v);
      w2p[(size_t)combo*256 + idx] = p ? f2bf(v - bf2f(hi)) : hi;
    }
  } else {
    // ---- Gm2: A-frags for rank-8 stage2 (|w4|-scaled, b3s in k=8 row).
    int idx = (blk-200)*256 + tid;          // [0, 8192)
    int j = idx & 7, lane = (idx >> 3) & 63, w = (idx >> 9) & 7, c = (idx >> 12) & 1;
    int h5 = lane >> 5, il = lane & 31;
    int n = 32*w + il;
    const float* w3 = c ? w3b : w3a;
    const float* w4 = c ? w4b : w4a;
    const float* b3 = c ? b3b : b3a;
    float aw = fabsf(w4[n]);
    float v;
    if (h5 == 0)     v = w3[(size_t)j*256 + n] * aw;
    else if (j == 0) v = b3[n] * aw;
    else             v = 0.f;
    Gm[idx] = f2bf(v);
  }
}

// ---------------------------------------------------------------------------
// enc_mfma: unchanged from R9/R12 (32 rows/block, 4 waves/SIMD).
// ---------------------------------------------------------------------------
__global__ __launch_bounds__(256, 4)
void enc_mfma(const float* __restrict__ state, const float* __restrict__ action,
              const unsigned short* __restrict__ w1p,
              const float* __restrict__ b1a, const float* __restrict__ b1b,
              const unsigned short* __restrict__ w2p,
              const float* __restrict__ b2a, const float* __restrict__ b2b,
              float* __restrict__ enc, int Bn) {
  __shared__ __align__(16) char Bx[2][8192];
  __shared__ __align__(16) float sb1[2][256];
  __shared__ float sb2[2][8];
  __shared__ __align__(16) float encw[4][32][8];
  int tid = threadIdx.x;
  int lane = tid & 63, w = tid >> 6, il = lane & 31, h5 = lane >> 5;
  int r0 = blockIdx.x * 32;

  sb1[0][tid] = b1a[tid];
  sb1[1][tid] = b1b[tid];
  if (tid < 8) { sb2[0][tid] = b2a[tid]; sb2[1][tid] = b2b[tid]; }

  {
    int m = tid >> 3, q8 = tid & 7;
    const float4* st4 = (const float4*)state;
    const float4* ac4 = (const float4*)action;
    #pragma unroll
    for (int j = 0; j < 4; ++j) {
      int f = j*8 + q8;                 // float4 slot 0..31 of the row
      int ks = f >> 2, kq = f & 3;
      float4 v = (ks < 6) ? st4[(size_t)(r0+m)*24 + ks*4 + kq]
                          : ac4[(size_t)(r0+m)*8 + (ks-6)*4 + kq];
      unsigned short hx = f2bf(v.x), hy = f2bf(v.y), hz = f2bf(v.z), hw = f2bf(v.w);
      uint2 hh, ll;
      hh.x = (unsigned)hx | ((unsigned)hy << 16);
      hh.y = (unsigned)hz | ((unsigned)hw << 16);
      ll.x = (unsigned)f2bf(v.x - bf2f(hx)) | ((unsigned)f2bf(v.y - bf2f(hy)) << 16);
      ll.y = (unsigned)f2bf(v.z - bf2f(hz)) | ((unsigned)f2bf(v.w - bf2f(hw)) << 16);
      int off = ks*1024 + m*32 + kq*8;
      *(uint2*)(&Bx[0][off]) = hh;
      *(uint2*)(&Bx[1][off]) = ll;
    }
  }
  __syncthreads();

  for (int c = 0; c < 2; ++c) {
    accv_t A[2] = {{},{}};
    #pragma unroll
    for (int ks = 0; ks < 8; ++ks) {
      bfrag_t a0h, a0l, a1h, a1l;
      {
        size_t b0 = ((size_t)((c*2+0)*8 + ks)*2 + h5)*256;
        size_t b1 = ((size_t)((c*2+1)*8 + ks)*2 + h5)*256;
        int t0 = 2*w, t1 = 2*w+1;
        a0h = *(const bfrag_t*)(w1p + (b0 + t0*32 + il)*8);
        a0l = *(const bfrag_t*)(w1p + (b1 + t0*32 + il)*8);
        a1h = *(const bfrag_t*)(w1p + (b0 + t1*32 + il)*8);
        a1l = *(const bfrag_t*)(w1p + (b1 + t1*32 + il)*8);
      }
      bfrag_t b0h = *(const bfrag_t*)(&Bx[0][ks*1024 + il*32 + h5*16]);
      bfrag_t b0l = *(const bfrag_t*)(&Bx[1][ks*1024 + il*32 + h5*16]);
      A[0] = __builtin_amdgcn_mfma_f32_32x32x16_bf16(a0h, b0h, A[0], 0,0,0);
      A[0] = __builtin_amdgcn_mfma_f32_32x32x16_bf16(a0h, b0l, A[0], 0,0,0);
      A[0] = __builtin_amdgcn_mfma_f32_32x32x16_bf16(a0l, b0h, A[0], 0,0,0);
      A[1] = __builtin_amdgcn_mfma_f32_32x32x16_bf16(a1h, b0h, A[1], 0,0,0);
      A[1] = __builtin_amdgcn_mfma_f32_32x32x16_bf16(a1h, b0l, A[1], 0,0,0);
      A[1] = __builtin_amdgcn_mfma_f32_32x32x16_bf16(a1l, b0h, A[1], 0,0,0);
    }
    #pragma unroll
    for (int nt = 0; nt < 2; ++nt) {
      #pragma unroll
      for (int g = 0; g < 4; ++g) {
        float4 bb = *(const float4*)&sb1[c][(2*w+nt)*32 + 8*g + 4*h5];
        float bba[4] = {bb.x, bb.y, bb.z, bb.w};
        #pragma unroll
        for (int jj = 0; jj < 4; ++jj) {
          A[nt][4*g+jj] = fmaxf(A[nt][4*g+jj] + bba[jj], 0.f);
        }
      }
    }
    accv_t Cm = {};
    #pragma unroll
    for (int k2 = 0; k2 < 4; ++k2) {
      int k16 = 4*w + k2;
      bfrag_t g2h = *(const bfrag_t*)(w2p + ((size_t)((c*2+0)*16 + k16)*2 + h5)*256 + il*8);
      bfrag_t g2l = *(const bfrag_t*)(w2p + ((size_t)((c*2+1)*16 + k16)*2 + h5)*256 + il*8);
      unsigned ph[2][2], pl[2][2];
      #pragma unroll
      for (int gi = 0; gi < 2; ++gi) {
        int G = 2*k2 + gi, nt = G >> 2, g = G & 3;
        float f0 = A[nt][4*g+0], f1 = A[nt][4*g+1];
        float f2 = A[nt][4*g+2], f3 = A[nt][4*g+3];
        unsigned short h0 = f2bf(f0), h1 = f2bf(f1), h2 = f2bf(f2), h3 = f2bf(f3);
        ph[gi][0] = (unsigned)h0 | ((unsigned)h1 << 16);
        ph[gi][1] = (unsigned)h2 | ((unsigned)h3 << 16);
        pl[gi][0] = (unsigned)f2bf(f0 - bf2f(h0)) | ((unsigned)f2bf(f1 - bf2f(h1)) << 16);
        pl[gi][1] = (unsigned)f2bf(f2 - bf2f(h2)) | ((unsigned)f2bf(f3 - bf2f(h3)) << 16);
      }
      union { bfrag_t v; unsigned u[4]; } FH, FL;
      #pragma unroll
      for (int r = 0; r < 2; ++r) {
        unsigned own_h = h5 ? ph[1][r] : ph[0][r];
        unsigned alt_h = h5 ? ph[0][r] : ph[1][r];
        unsigned rec_h = __shfl_xor((int)alt_h, 32);
        FH.u[r]   = h5 ? rec_h : own_h;
        FH.u[2+r] = h5 ? own_h : rec_h;
        unsigned own_l = h5 ? pl[1][r] : pl[0][r];
        unsigned alt_l = h5 ? pl[0][r] : pl[1][r];
        unsigned rec_l = __shfl_xor((int)alt_l, 32);
        FL.u[r]   = h5 ? rec_l : own_l;
        FL.u[2+r] = h5 ? own_l : rec_l;
      }
      Cm = __builtin_amdgcn_mfma_f32_32x32x16_bf16(g2h, FH.v, Cm, 0,0,0);
      Cm = __builtin_amdgcn_mfma_f32_32x32x16_bf16(g2h, FL.v, Cm, 0,0,0);
      Cm = __builtin_amdgcn_mfma_f32_32x32x16_bf16(g2l, FH.v, Cm, 0,0,0);
    }
    *(float4*)&encw[w][il][4*h5] = make_float4(Cm[0], Cm[1], Cm[2], Cm[3]);
    __syncthreads();
    {
      int e = tid & 7, mm = tid >> 3;
      float v = sb2[c][e];
      #pragma unroll
      for (int ww = 0; ww < 4; ++ww) v += encw[ww][mm][e];
      enc[((size_t)c*Bn + r0 + mm)*8 + e] = v;
    }
    __syncthreads();
  }
}

// ---------------------------------------------------------------------------
// qgemm R13 helpers (a_build: R6-validated FP order, unchanged)
// ---------------------------------------------------------------------------
__device__ __forceinline__ void a_build(float4 ea, float4 eb, char* Ab, int ag2, int am) {
  float c0,s0,c1,s1,c2,s2,c3,s3,c4,s4,c5,s5,c6,s6,c7,s7;
  __sincosf(0.5f*ea.x, &s0, &c0);
  __sincosf(0.5f*ea.y, &s1, &c1);
  __sincosf(0.5f*ea.z, &s2, &c2);
  __sincosf(0.5f*ea.w, &s3, &c3);
  __sincosf(0.5f*eb.x, &s4, &c4);
  __sincosf(0.5f*eb.y, &s5, &c5);
  __sincosf(0.5f*eb.z, &s6, &c6);
  __sincosf(0.5f*eb.w, &s7, &c7);
  float v0 = (ag2&8) ? s0 : c0;
  float v1 = (ag2&4) ? s1 : c1;
  float v2 = (ag2&2) ? s2 : c2;
  float v3 = (ag2&1) ? s3 : c3;
  float top = v0*v1*v2*v3;
  float hA = top*c4, hB = top*s4;
  float p67[4];
  p67[0] = c6*c7; p67[1] = c6*s7; p67[2] = s6*c7; p67[3] = s6*s7;
  float low[8];
  #pragma unroll
  for (int j = 0; j < 8; ++j) low[j] = ((j&4) ? s5 : c5) * p67[j&3];
  union { bfrag_t v; unsigned u[4]; } pk;
  #pragma unroll
  for (int k = 0; k < 4; ++k) pk.u[k] = pack2(hA*low[2*k], hA*low[2*k+1]);
  *(bfrag_t*)(Ab + ag2*1024 + am*16) = pk.v;
  #pragma unroll
  for (int k = 0; k < 4; ++k) pk.u[k] = pack2(hB*low[2*k], hB*low[2*k+1]);
  *(bfrag_t*)(Ab + ag2*1024 + 512 + am*16) = pk.v;
}

// ---------------------------------------------------------------------------
// qgemm R13: 512 thr = 8 waves, grid 256, 4 iters of 128 rows (4 subs).
// Per iter: S1 x4 subs (swapped MFMA, ex bit-sign partials -> exw) | B2 |
// deferred out(prev) + exw->exf reduce WITH bf16 pack + A-build x4(next) |
// B3 | S2 x4 (1 MFMA each vs resident w3-frag; fa = 1 b128 read) + qp.
// 2 barriers/iter (8 total). LDS 111KB.
// ---------------------------------------------------------------------------
__global__ __launch_bounds__(512, 2)
void qgemm(const float* __restrict__ enc,
           const unsigned short* __restrict__ Bm, const unsigned short* __restrict__ Gm,
           const float* __restrict__ b3a, const float* __restrict__ w4a, const float* __restrict__ b4a,
           const float* __restrict__ b3b, const float* __restrict__ w4b, const float* __restrict__ b4b,
           float* __restrict__ out, int Bn) {
  __shared__ __align__(16) char APq[111104];
  char* Abase = APq;                       // [sub*16384 + g2*1024 + half*512 + m*16]
  float* exw = (float*)(APq + 65536);      // [sub*2304 + w*288 + m*9 + q] f32
  unsigned* exf = (unsigned*)(APq + 102400); // [sub*256 + m*8 + k2] u32 (bf16 pair)
  float* qp  = (float*)(APq + 106496);     // [row*9 + w] f32 (128x9)

  int tid = threadIdx.x;
  int lane = tid & 63;
  int w = tid >> 6;
  int il = lane & 31;
  int h5 = lane >> 5;

  int c = blockIdx.x >> 7;
  int rowblock = blockIdx.x & 127;
  int rowsPerBlock = Bn >> 7;        // 512
  int niter = rowsPerBlock >> 7;     // 4

  // ---- persistent W-frags: tile pair (w, 8+w), 128 regs ----
  bfrag_t bf0[16], bf1[16];
  {
    const unsigned short* base = Bm + ((size_t)(c*512 + 32*w + il)*256 + h5*8);
    #pragma unroll
    for (int ks = 0; ks < 16; ++ks) {
      bf0[ks] = *(const bfrag_t*)(base + ks*16);
      bf1[ks] = *(const bfrag_t*)(base + 256*256 + ks*16);
    }
  }
  // resident w3s/b3s A-frag (4 VGPRs)
  bfrag_t gf2 = *(const bfrag_t*)(Gm + ((size_t)((c*8 + w)*64 + lane))*8);

  int n2 = 32*w + il;
  const float* w4c = c ? w4b : w4a;
  const float* b4c = c ? b4b : b4a;
  float w4v = w4c[n2];
  float b4v = b4c[0];
  // sign mask for the wave's 32-col w4 slice (bits = il, duplicated 32-63)
  unsigned smask = (unsigned)__ballot(w4v < 0.f);

  int am = tid & 31, ag2 = tid >> 5;
  const float* encb = enc + ((size_t)c*Bn)*8;
  int rbase = rowblock*rowsPerBlock;

  // ---- prologue: A-build for first 128 rows ----
  #pragma unroll
  for (int sub = 0; sub < 4; ++sub) {
    const float* ep = encb + (size_t)(rbase + sub*32 + am)*8;
    float4 pa = *(const float4*)ep, pb = *(const float4*)(ep + 4);
    a_build(pa, pb, Abase + sub*16384, ag2, am);
  }
  __syncthreads();

  for (int st = 0; st < niter; ++st) {
    int r0 = rbase + st*128;
    // ===== phase1: stage1 x4 subs, swapped operands; ex partials =====
    #pragma unroll
    for (int sub = 0; sub < 4; ++sub) {
      const char* Asel = Abase + sub*16384;
      accv_t acc0 = {}, acc1 = {};
      #pragma unroll
      for (int ks = 0; ks < 16; ++ks) {
        bfrag_t af = *(const bfrag_t*)(Asel + ks*1024 + lane*16);
        acc0 = __builtin_amdgcn_mfma_f32_32x32x16_bf16(bf0[ks], af, acc0, 0, 0, 0);
        acc1 = __builtin_amdgcn_mfma_f32_32x32x16_bf16(bf1[ks], af, acc1, 0, 0, 0);
      }
      // lane holds P[i_local(r,h5)][m=il]; i bits: 0-1=r&3, 2=h5, 3-4=r>>2
      float Pv[16];
      #pragma unroll
      for (int r = 0; r < 16; ++r) Pv[r] = acc0[r]*acc0[r] + acc1[r]*acc1[r];
      float E  = ((Pv[0]+Pv[1])+(Pv[2]+Pv[3])) + ((Pv[4]+Pv[5])+(Pv[6]+Pv[7]));
      float S4 = ((Pv[8]+Pv[9])+(Pv[10]+Pv[11])) + ((Pv[12]+Pv[13])+(Pv[14]+Pv[15]));
      float T  = E + S4;
      float S0 = ((Pv[1]+Pv[3])+(Pv[5]+Pv[7])) + ((Pv[9]+Pv[11])+(Pv[13]+Pv[15]));
      float S1 = ((Pv[2]+Pv[3])+(Pv[6]+Pv[7])) + ((Pv[10]+Pv[11])+(Pv[14]+Pv[15]));
      float S3 = ((Pv[4]+Pv[5])+(Pv[6]+Pv[7])) + ((Pv[12]+Pv[13])+(Pv[14]+Pv[15]));
      float e[8];
      e[7] = T - 2.f*S0;           // q=7 <- i bit0
      e[6] = T - 2.f*S1;           // bit1
      e[5] = h5 ? -T : T;          // bit2 = h5
      e[4] = T - 2.f*S3;           // bit3
      e[3] = T - 2.f*S4;           // bit4
      e[2] = (w&1) ? -T : T;       // bit5
      e[1] = (w&2) ? -T : T;       // bit6
      e[0] = (w&4) ? -T : T;       // bit7
      #pragma unroll
      for (int q = 0; q < 8; ++q) e[q] += __shfl_xor(e[q], 32);
      if (h5 == 0) {
        float* dst = exw + sub*2304 + w*288 + il*9;
        #pragma unroll
        for (int q = 0; q < 8; ++q) dst[q] = e[q];
      }
    }
    __syncthreads();                                   // B2: exw ready, A reads done
    // ===== phase2: deferred out(prev) + exw->exf(bf16-packed) + A-build =====
    if (st > 0 && tid < 128) {
      const float* qr = qp + tid*9;
      float s = ((qr[0]+qr[1]) + (qr[2]+qr[3])) + ((qr[4]+qr[5]) + (qr[6]+qr[7]));
      out[(size_t)c*Bn + (r0 - 128) + tid] = s + b4v;
    }
    {
      // thread -> (sub = t>>7, m = (t>>2)&31, k2 = t&3): two q sums + pack
      int sub = tid >> 7, m = (tid >> 2) & 31, k2 = tid & 3;
      const float* ew0 = exw + sub*2304 + m*9 + 2*k2;
      float s0 = ((ew0[0] + ew0[288]) + (ew0[2*288] + ew0[3*288]))
               + ((ew0[4*288] + ew0[5*288]) + (ew0[6*288] + ew0[7*288]));
      const float* ew1 = ew0 + 1;
      float s1 = ((ew1[0] + ew1[288]) + (ew1[2*288] + ew1[3*288]))
               + ((ew1[4*288] + ew1[5*288]) + (ew1[6*288] + ew1[7*288]));
      exf[sub*256 + m*8 + k2] = pack2(s0, s1);
    }
    bool more = (st + 1 < niter);
    if (more) {
      #pragma unroll
      for (int sub = 0; sub < 4; ++sub) {
        const float* ep = encb + (size_t)(r0 + 128 + sub*32 + am)*8;
        float4 pa = *(const float4*)ep, pb = *(const float4*)(ep + 4);
        a_build(pa, pb, Abase + sub*16384, ag2, am);
      }
    }
    __syncthreads();                                   // B3: exf + next-A ready
    // ===== phase3: stage2 x4 (lane=m, r=n; bias in k=8 row) + qp =====
    #pragma unroll
    for (int sub = 0; sub < 4; ++sub) {
      union { bfrag_t v; unsigned u[4]; } fa;
      if (h5 == 0) {
        fa.v = *(const bfrag_t*)(exf + sub*256 + il*8);
      } else {
        // k=8 bias row: constant 1.0 multiplies Gm2's b3s row
        fa.u[0] = 0x00003F80u; fa.u[1]=0; fa.u[2]=0; fa.u[3]=0;
      }
      accv_t acc2 = {};
      acc2 = __builtin_amdgcn_mfma_f32_32x32x16_bf16(gf2, fa.v, acc2, 0, 0, 0);
      // lane = batch m (=il); r = n_local = (r&3)+8*(r>>2)+4*h5 in wave slice
      float qa = 0.f;
      #pragma unroll
      for (int r = 0; r < 16; ++r) {
        int bi = (r&3) + 8*(r>>2);
        float ta = fmaxf(acc2[r], 0.f);
        bool neg = ((smask >> (bi + 4*h5)) & 1u) != 0u;
        qa += neg ? -ta : ta;
      }
      qa += __shfl_xor(qa, 32);
      if (h5 == 0) qp[(sub*32 + il)*9 + w] = qa;
    }
    // no barrier: next phase1 writes exw (last read pre-B3), reads A
    // (built phase2, post-B3); qp read is after next B2.
  }
  // ---- epilogue: out-write for the last iteration ----
  __syncthreads();
  if (tid < 128) {
    const float* qr = qp + tid*9;
    float s = ((qr[0]+qr[1]) + (qr[2]+qr[3])) + ((qr[4]+qr[5]) + (qr[6]+qr[7]));
    out[(size_t)c*Bn + rbase + (niter-1)*128 + tid] = s + b4v;
  }
}

extern "C" void kernel_launch(void* const* d_in, const int* in_sizes, int n_in,
                              void* d_out, int out_size, void* d_ws, size_t ws_size,
                              hipStream_t stream) {
  (void)n_in; (void)out_size; (void)ws_size;
  const float* state  = (const float*)d_in[0];
  const float* action = (const float*)d_in[1];
  const float* w1a=(const float*)d_in[2];  const float* b1a=(const float*)d_in[3];
  const float* w2a=(const float*)d_in[4];  const float* b2a=(const float*)d_in[5];
  const float* qrxa=(const float*)d_in[6]; const float* qrya=(const float*)d_in[7];
  const float* qrza=(const float*)d_in[8];
  const float* w3a=(const float*)d_in[9];  const float* b3a=(const float*)d_in[10];
  const float* w4a=(const float*)d_in[11]; const float* b4a=(const float*)d_in[12];
  const float* w1b=(const float*)d_in[13]; const float* b1b=(const float*)d_in[14];
  const float* w2b=(const float*)d_in[15]; const float* b2b=(const float*)d_in[16];
  const float* qrxb=(const float*)d_in[17];const float* qryb=(const float*)d_in[18];
  const float* qrzb=(const float*)d_in[19];
  const float* w3b=(const float*)d_in[20]; const float* b3b=(const float*)d_in[21];
  const float* w4b=(const float*)d_in[22]; const float* b4b=(const float*)d_in[23];

  int B = in_sizes[0] / 96;
  char* wsb = (char*)d_ws;
  unsigned short* Bmat = (unsigned short*)(wsb);                 // 524288 B
  unsigned short* Gmat = (unsigned short*)(wsb + 524288);        // 16384 B used
  unsigned short* w1p  = (unsigned short*)(wsb + 786432);        // 262144 B
  unsigned short* w2p  = (unsigned short*)(wsb + 1048576);       // 65536 B
  float* enc           = (float*)(wsb + 1114112);                // 2*B*8*4 B

  prep_weights<<<232, 256, 0, stream>>>(qrxa,qrya,qrza,qrxb,qryb,qrzb,
                                        w1a,w1b,w2a,w2b,w3a,w3b,w4a,w4b,b3a,b3b,
                                        Bmat,Gmat,w1p,w2p);
  enc_mfma<<<B/32, 256, 0, stream>>>(state,action,w1p,b1a,b1b,w2p,b2a,b2b,enc,B);
  qgemm<<<256, 512, 0, stream>>>(enc, Bmat, Gmat, b3a, w4a, b4a, b3b, w4b, b4b,
                                 (float*)d_out, B);
}

// Round 11
// 190.515 us; speedup vs baseline: 1.2608x; 1.0422x over previous
//
#include <hip/hip_runtime.h>
#include <math.h>

// ---------------------------------------------------------------------------
// QuantumCritic R14.
//   psi = W r ; P = |psi|^2 ; ex[q] = sum_i sign(i,q) P[i] (rank-8)
//   q = sum_n sign(w4[n]) * relu(ex.(w3[:,n]|w4[n]|) + b3[n]|w4[n]|) + b4
// R14 changes vs R13 (post-mortem: total - qgemm clusters at ~139us for the
// 64-row enc_mfma (R4-R7b) vs ~150us for the 32-row enc (R9-R13) — the R9
// enc "occupancy fix" was a ~10us net regression (2x blocks -> 2x w1p/w2p
// L2 re-reads outweighed the 4-waves/SIMD gain), never verified in
// isolation until now):
//   - enc_mfma: REVERTED to the R6-validated 64-row version
//     (launch_bounds(256,2), grid B/64, Bx[2][16384], mt dimension).
//   - qgemm, prep_weights: byte-identical to R13 (validated 50.3us).
// ---------------------------------------------------------------------------

typedef __attribute__((ext_vector_type(8))) short bfrag_t;   // 8 bf16 = 4 VGPR
typedef __attribute__((ext_vector_type(16))) float accv_t;   // 32x32 MFMA acc

__device__ __forceinline__ unsigned short f2bf(float x) {
  unsigned u = __float_as_uint(x);
  u += 0x7FFFu + ((u >> 16) & 1u);      // RNE
  return (unsigned short)(u >> 16);
}
__device__ __forceinline__ float bf2f(unsigned short h) {
  return __uint_as_float(((unsigned)h) << 16);
}
__device__ __forceinline__ unsigned pack2(float a, float b) {
  return (unsigned)f2bf(a) | ((unsigned)f2bf(b) << 16);
}

struct C2 { float r, i; };
__device__ __forceinline__ C2 cmul(C2 a, C2 b){ return C2{a.r*b.r - a.i*b.i, a.r*b.i + a.i*b.r}; }
__device__ __forceinline__ C2 cadd(C2 a, C2 b){ return C2{a.r+b.r, a.i+b.i}; }

#define APPLY2(A,Bx)                                                        \
  { float ar=re[A], ai=im[A], br=re[Bx], bi=im[Bx];                         \
    re[A]  = u00r*ar - u00i*ai + u01r*br - u01i*bi;                         \
    im[A]  = u00r*ai + u00i*ar + u01r*bi + u01i*br;                         \
    re[Bx] = u10r*ar - u10i*ai + u11r*br - u11i*bi;                         \
    im[Bx] = u10r*ai + u10i*ar + u11r*bi + u11i*br; }

__global__ __launch_bounds__(256)
void prep_weights(const float* __restrict__ qrxa, const float* __restrict__ qrya,
                  const float* __restrict__ qrza,
                  const float* __restrict__ qrxb, const float* __restrict__ qryb,
                  const float* __restrict__ qrzb,
                  const float* __restrict__ w1a, const float* __restrict__ w1b,
                  const float* __restrict__ w2a, const float* __restrict__ w2b,
                  const float* __restrict__ w3a, const float* __restrict__ w3b,
                  const float* __restrict__ w4a, const float* __restrict__ w4b,
                  const float* __restrict__ b3a, const float* __restrict__ b3b,
                  unsigned short* __restrict__ Bm, unsigned short* __restrict__ Gm,
                  unsigned short* __restrict__ w1p, unsigned short* __restrict__ w2p) {
  int blk = blockIdx.x;
  int tid = threadIdx.x;
  if (blk < 128) {
    // ---- prep_W: circuit on 256 basis columns ----
    __shared__ float sg[192];
    int c = blk >> 6;
    if (tid < 24) {
      const float* qx = c ? qrxb : qrxa;
      const float* qy = c ? qryb : qrya;
      const float* qz = c ? qrzb : qrza;
      int g = tid;
      float tx = 0.5f*qx[g], ty = 0.5f*qy[g], tz = 0.5f*qz[g];
      float cx = cosf(tx), sx = sinf(tx);
      float cy = cosf(ty), sy = sinf(ty);
      float cz = cosf(tz), sz = sinf(tz);
      C2 rx00{cx,0.f}, rx01{0.f,-sx}, rx10{0.f,-sx}, rx11{cx,0.f};
      C2 m00 = cadd(cmul(C2{cy,0.f},rx00), cmul(C2{-sy,0.f},rx10));
      C2 m01 = cadd(cmul(C2{cy,0.f},rx01), cmul(C2{-sy,0.f},rx11));
      C2 m10 = cadd(cmul(C2{sy,0.f},rx00), cmul(C2{cy,0.f},rx10));
      C2 m11 = cadd(cmul(C2{sy,0.f},rx01), cmul(C2{cy,0.f},rx11));
      C2 e0{cz,-sz}, e1{cz,sz};
      C2 u00 = cmul(e0,m00), u01 = cmul(e0,m01), u10 = cmul(e1,m10), u11 = cmul(e1,m11);
      float* o = sg + g*8;
      o[0]=u00.r; o[1]=u00.i; o[2]=u01.r; o[3]=u01.i;
      o[4]=u10.r; o[5]=u10.i; o[6]=u11.r; o[7]=u11.i;
    }
    __syncthreads();
    int lane = tid & 63;
    int wid = blk*4 + (tid >> 6);
    int bcol = wid & 255;
    int p = __popc(bcol) & 3;
    float phr = (p==0) ? 1.f : ((p==2) ? -1.f : 0.f);
    float phi = (p==1) ? -1.f : ((p==3) ? 1.f : 0.f);
    float re[4], im[4];
    #pragma unroll
    for (int j = 0; j < 4; ++j) {
      int idx = 4*lane + j;
      re[j] = (idx==bcol) ? phr : 0.f;
      im[j] = (idx==bcol) ? phi : 0.f;
    }
    #pragma unroll
    for (int l = 0; l < 3; ++l) {
      #pragma unroll
      for (int q = 0; q < 8; ++q) {
        const float* u = &sg[(size_t)(l*8 + q)*8];
        float u00r=u[0],u00i=u[1],u01r=u[2],u01i=u[3];
        float u10r=u[4],u10i=u[5],u11r=u[6],u11i=u[7];
        if (q < 6) {
          int m = 5-q, mask = 1<<m;
          bool s1 = ((lane >> m) & 1) != 0;
          float udr = s1?u11r:u00r, udi = s1?u11i:u00i;
          float uor = s1?u10r:u01r, uoi = s1?u10i:u01i;
          #pragma unroll
          for (int j = 0; j < 4; ++j) {
            float pr = __shfl_xor(re[j], mask);
            float pi = __shfl_xor(im[j], mask);
            float nr = udr*re[j] - udi*im[j] + uor*pr - uoi*pi;
            float ni = udr*im[j] + udi*re[j] + uor*pi + uoi*pr;
            re[j]=nr; im[j]=ni;
          }
        } else if (q == 6) { APPLY2(0,2); APPLY2(1,3); }
        else               { APPLY2(0,1); APPLY2(2,3); }
      }
      #pragma unroll
      for (int cq = 0; cq <= 4; ++cq) {
        int tmask = 1 << (4-cq);
        bool pred = ((lane >> (5-cq)) & 1) != 0;
        #pragma unroll
        for (int j = 0; j < 4; ++j) {
          float sr = __shfl_xor(re[j], tmask);
          float si = __shfl_xor(im[j], tmask);
          re[j] = pred ? sr : re[j];
          im[j] = pred ? si : im[j];
        }
      }
      { bool pred = (lane & 1) != 0;
        float t0, t1;
        t0 = pred?re[2]:re[0]; t1 = pred?re[0]:re[2]; re[0]=t0; re[2]=t1;
        t0 = pred?im[2]:im[0]; t1 = pred?im[0]:im[2]; im[0]=t0; im[2]=t1;
        t0 = pred?re[3]:re[1]; t1 = pred?re[1]:re[3]; re[1]=t0; re[3]=t1;
        t0 = pred?im[3]:im[1]; t1 = pred?im[1]:im[3]; im[1]=t0; im[3]=t1; }
      { float t;
        t=re[2]; re[2]=re[3]; re[3]=t;
        t=im[2]; im[2]=im[3]; im[3]=t; }
      { re[1]=__shfl_xor(re[1],32); im[1]=__shfl_xor(im[1],32);
        re[3]=__shfl_xor(re[3],32); im[3]=__shfl_xor(im[3],32); }
    }
    #pragma unroll
    for (int j = 0; j < 4; ++j) {
      int i = 4*lane + j;
      Bm[(size_t)(c*512 + i)*256 + bcol]       = f2bf(re[j]);
      Bm[(size_t)(c*512 + 256 + i)*256 + bcol] = f2bf(im[j]);
    }
  } else if (blk < 192) {
    // ---- w1pack ----
    int slot = (blk-128)*256 + tid;
    int n = slot & 255, h5 = (slot>>8)&1, ks = (slot>>9)&7, p = (slot>>12)&1, c = slot>>13;
    const float* w1c = c ? w1b : w1a;
    #pragma unroll
    for (int j = 0; j < 8; ++j) {
      float v = w1c[(size_t)(ks*16 + h5*8 + j)*256 + n];
      unsigned short hi = f2bf(v);
      w1p[(size_t)slot*8 + j] = p ? f2bf(v - bf2f(hi)) : hi;
    }
  } else if (blk < 200) {
    // ---- w2pack ----
    int slot = (blk-192)*256 + tid;
    int combo = slot >> 4, part = slot & 15;
    int h5 = combo&1, k16 = (combo>>1)&15, p = (combo>>5)&1, c = (combo>>6)&1;
    const float* w2c = c ? w2b : w2a;
    #pragma unroll
    for (int jj = 0; jj < 16; ++jj) {
      int idx = part*16 + jj;
      int il = idx >> 3, j = idx & 7;
      int n = k16*16 + h5*8 + j;
      float v = (il < 8) ? w2c[(size_t)n*8 + il] : 0.f;
      unsigned short hi = f2bf(v);
      w2p[(size_t)combo*256 + idx] = p ? f2bf(v - bf2f(hi)) : hi;
    }
  } else {
    // ---- Gm2: A-frags for rank-8 stage2 (|w4|-scaled, b3s in k=8 row).
    int idx = (blk-200)*256 + tid;          // [0, 8192)
    int j = idx & 7, lane = (idx >> 3) & 63, w = (idx >> 9) & 7, c = (idx >> 12) & 1;
    int h5 = lane >> 5, il = lane & 31;
    int n = 32*w + il;
    const float* w3 = c ? w3b : w3a;
    const float* w4 = c ? w4b : w4a;
    const float* b3 = c ? b3b : b3a;
    float aw = fabsf(w4[n]);
    float v;
    if (h5 == 0)     v = w3[(size_t)j*256 + n] * aw;
    else if (j == 0) v = b3[n] * aw;
    else             v = 0.f;
    Gm[idx] = f2bf(v);
  }
}

// ---------------------------------------------------------------------------
// enc_mfma: R6-validated 64-row version (reverted from R9's 32-row split —
// the split cost ~10us in w1p/w2p L2 re-reads).
// ---------------------------------------------------------------------------
__global__ __launch_bounds__(256, 2)
void enc_mfma(const float* __restrict__ state, const float* __restrict__ action,
              const unsigned short* __restrict__ w1p,
              const float* __restrict__ b1a, const float* __restrict__ b1b,
              const unsigned short* __restrict__ w2p,
              const float* __restrict__ b2a, const float* __restrict__ b2b,
              float* __restrict__ enc, int Bn) {
  __shared__ __align__(16) char Bx[2][16384];
  __shared__ __align__(16) float sb1[2][256];
  __shared__ float sb2[2][8];
  __shared__ __align__(16) float encw[4][2][32][8];
  int tid = threadIdx.x;
  int lane = tid & 63, w = tid >> 6, il = lane & 31, h5 = lane >> 5;
  int r0 = blockIdx.x * 64;

  sb1[0][tid] = b1a[tid];
  sb1[1][tid] = b1b[tid];
  if (tid < 8) { sb2[0][tid] = b2a[tid]; sb2[1][tid] = b2b[tid]; }

  {
    int m = tid >> 2, kq = tid & 3;
    const float4* st4 = (const float4*)state;
    const float4* ac4 = (const float4*)action;
    #pragma unroll
    for (int ks = 0; ks < 8; ++ks) {
      float4 v = (ks < 6) ? st4[(size_t)(r0+m)*24 + ks*4 + kq]
                          : ac4[(size_t)(r0+m)*8 + (ks-6)*4 + kq];
      unsigned short hx = f2bf(v.x), hy = f2bf(v.y), hz = f2bf(v.z), hw = f2bf(v.w);
      uint2 hh, ll;
      hh.x = (unsigned)hx | ((unsigned)hy << 16);
      hh.y = (unsigned)hz | ((unsigned)hw << 16);
      ll.x = (unsigned)f2bf(v.x - bf2f(hx)) | ((unsigned)f2bf(v.y - bf2f(hy)) << 16);
      ll.y = (unsigned)f2bf(v.z - bf2f(hz)) | ((unsigned)f2bf(v.w - bf2f(hw)) << 16);
      int off = ks*2048 + m*32 + kq*8;
      *(uint2*)(&Bx[0][off]) = hh;
      *(uint2*)(&Bx[1][off]) = ll;
    }
  }
  __syncthreads();

  for (int c = 0; c < 2; ++c) {
    accv_t A[2][2] = {{{},{}},{{},{}}};
    #pragma unroll
    for (int ks = 0; ks < 8; ++ks) {
      bfrag_t a0h, a0l, a1h, a1l;
      {
        size_t b0 = ((size_t)((c*2+0)*8 + ks)*2 + h5)*256;
        size_t b1 = ((size_t)((c*2+1)*8 + ks)*2 + h5)*256;
        int t0 = 2*w, t1 = 2*w+1;
        a0h = *(const bfrag_t*)(w1p + (b0 + t0*32 + il)*8);
        a0l = *(const bfrag_t*)(w1p + (b1 + t0*32 + il)*8);
        a1h = *(const bfrag_t*)(w1p + (b0 + t1*32 + il)*8);
        a1l = *(const bfrag_t*)(w1p + (b1 + t1*32 + il)*8);
      }
      bfrag_t b0h = *(const bfrag_t*)(&Bx[0][ks*2048 + il*32 + h5*16]);
      bfrag_t b0l = *(const bfrag_t*)(&Bx[1][ks*2048 + il*32 + h5*16]);
      bfrag_t b1h_ = *(const bfrag_t*)(&Bx[0][ks*2048 + (32+il)*32 + h5*16]);
      bfrag_t b1l_ = *(const bfrag_t*)(&Bx[1][ks*2048 + (32+il)*32 + h5*16]);
      A[0][0] = __builtin_amdgcn_mfma_f32_32x32x16_bf16(a0h, b0h, A[0][0], 0,0,0);
      A[0][0] = __builtin_amdgcn_mfma_f32_32x32x16_bf16(a0h, b0l, A[0][0], 0,0,0);
      A[0][0] = __builtin_amdgcn_mfma_f32_32x32x16_bf16(a0l, b0h, A[0][0], 0,0,0);
      A[0][1] = __builtin_amdgcn_mfma_f32_32x32x16_bf16(a0h, b1h_, A[0][1], 0,0,0);
      A[0][1] = __builtin_amdgcn_mfma_f32_32x32x16_bf16(a0h, b1l_, A[0][1], 0,0,0);
      A[0][1] = __builtin_amdgcn_mfma_f32_32x32x16_bf16(a0l, b1h_, A[0][1], 0,0,0);
      A[1][0] = __builtin_amdgcn_mfma_f32_32x32x16_bf16(a1h, b0h, A[1][0], 0,0,0);
      A[1][0] = __builtin_amdgcn_mfma_f32_32x32x16_bf16(a1h, b0l, A[1][0], 0,0,0);
      A[1][0] = __builtin_amdgcn_mfma_f32_32x32x16_bf16(a1l, b0h, A[1][0], 0,0,0);
      A[1][1] = __builtin_amdgcn_mfma_f32_32x32x16_bf16(a1h, b1h_, A[1][1], 0,0,0);
      A[1][1] = __builtin_amdgcn_mfma_f32_32x32x16_bf16(a1h, b1l_, A[1][1], 0,0,0);
      A[1][1] = __builtin_amdgcn_mfma_f32_32x32x16_bf16(a1l, b1h_, A[1][1], 0,0,0);
    }
    #pragma unroll
    for (int nt = 0; nt < 2; ++nt) {
      #pragma unroll
      for (int g = 0; g < 4; ++g) {
        float4 bb = *(const float4*)&sb1[c][(2*w+nt)*32 + 8*g + 4*h5];
        float bba[4] = {bb.x, bb.y, bb.z, bb.w};
        #pragma unroll
        for (int jj = 0; jj < 4; ++jj) {
          A[nt][0][4*g+jj] = fmaxf(A[nt][0][4*g+jj] + bba[jj], 0.f);
          A[nt][1][4*g+jj] = fmaxf(A[nt][1][4*g+jj] + bba[jj], 0.f);
        }
      }
    }
    accv_t Cm[2] = {{},{}};
    #pragma unroll
    for (int k2 = 0; k2 < 4; ++k2) {
      int k16 = 4*w + k2;
      bfrag_t g2h = *(const bfrag_t*)(w2p + ((size_t)((c*2+0)*16 + k16)*2 + h5)*256 + il*8);
      bfrag_t g2l = *(const bfrag_t*)(w2p + ((size_t)((c*2+1)*16 + k16)*2 + h5)*256 + il*8);
      #pragma unroll
      for (int mt = 0; mt < 2; ++mt) {
        unsigned ph[2][2], pl[2][2];
        #pragma unroll
        for (int gi = 0; gi < 2; ++gi) {
          int G = 2*k2 + gi, nt = G >> 2, g = G & 3;
          float f0 = A[nt][mt][4*g+0], f1 = A[nt][mt][4*g+1];
          float f2 = A[nt][mt][4*g+2], f3 = A[nt][mt][4*g+3];
          unsigned short h0 = f2bf(f0), h1 = f2bf(f1), h2 = f2bf(f2), h3 = f2bf(f3);
          ph[gi][0] = (unsigned)h0 | ((unsigned)h1 << 16);
          ph[gi][1] = (unsigned)h2 | ((unsigned)h3 << 16);
          pl[gi][0] = (unsigned)f2bf(f0 - bf2f(h0)) | ((unsigned)f2bf(f1 - bf2f(h1)) << 16);
          pl[gi][1] = (unsigned)f2bf(f2 - bf2f(h2)) | ((unsigned)f2bf(f3 - bf2f(h3)) << 16);
        }
        union { bfrag_t v; unsigned u[4]; } FH, FL;
        #pragma unroll
        for (int r = 0; r < 2; ++r) {
          unsigned own_h = h5 ? ph[1][r] : ph[0][r];
          unsigned alt_h = h5 ? ph[0][r] : ph[1][r];
          unsigned rec_h = __shfl_xor((int)alt_h, 32);
          FH.u[r]   = h5 ? rec_h : own_h;
          FH.u[2+r] = h5 ? own_h : rec_h;
          unsigned own_l = h5 ? pl[1][r] : pl[0][r];
          unsigned alt_l = h5 ? pl[0][r] : pl[1][r];
          unsigned rec_l = __shfl_xor((int)alt_l, 32);
          FL.u[r]   = h5 ? rec_l : own_l;
          FL.u[2+r] = h5 ? own_l : rec_l;
        }
        Cm[mt] = __builtin_amdgcn_mfma_f32_32x32x16_bf16(g2h, FH.v, Cm[mt], 0,0,0);
        Cm[mt] = __builtin_amdgcn_mfma_f32_32x32x16_bf16(g2h, FL.v, Cm[mt], 0,0,0);
        Cm[mt] = __builtin_amdgcn_mfma_f32_32x32x16_bf16(g2l, FH.v, Cm[mt], 0,0,0);
      }
    }
    *(float4*)&encw[w][0][il][4*h5] = make_float4(Cm[0][0], Cm[0][1], Cm[0][2], Cm[0][3]);
    *(float4*)&encw[w][1][il][4*h5] = make_float4(Cm[1][0], Cm[1][1], Cm[1][2], Cm[1][3]);
    __syncthreads();
    #pragma unroll
    for (int half = 0; half < 2; ++half) {
      int s = tid + half*256;
      int e = s & 7, mm = s >> 3;
      float v = sb2[c][e];
      #pragma unroll
      for (int ww = 0; ww < 4; ++ww) v += encw[ww][mm>>5][mm&31][e];
      enc[((size_t)c*Bn + r0 + mm)*8 + e] = v;
    }
    __syncthreads();
  }
}

// ---------------------------------------------------------------------------
// qgemm R13 helpers (a_build: R6-validated FP order, unchanged)
// ---------------------------------------------------------------------------
__device__ __forceinline__ void a_build(float4 ea, float4 eb, char* Ab, int ag2, int am) {
  float c0,s0,c1,s1,c2,s2,c3,s3,c4,s4,c5,s5,c6,s6,c7,s7;
  __sincosf(0.5f*ea.x, &s0, &c0);
  __sincosf(0.5f*ea.y, &s1, &c1);
  __sincosf(0.5f*ea.z, &s2, &c2);
  __sincosf(0.5f*ea.w, &s3, &c3);
  __sincosf(0.5f*eb.x, &s4, &c4);
  __sincosf(0.5f*eb.y, &s5, &c5);
  __sincosf(0.5f*eb.z, &s6, &c6);
  __sincosf(0.5f*eb.w, &s7, &c7);
  float v0 = (ag2&8) ? s0 : c0;
  float v1 = (ag2&4) ? s1 : c1;
  float v2 = (ag2&2) ? s2 : c2;
  float v3 = (ag2&1) ? s3 : c3;
  float top = v0*v1*v2*v3;
  float hA = top*c4, hB = top*s4;
  float p67[4];
  p67[0] = c6*c7; p67[1] = c6*s7; p67[2] = s6*c7; p67[3] = s6*s7;
  float low[8];
  #pragma unroll
  for (int j = 0; j < 8; ++j) low[j] = ((j&4) ? s5 : c5) * p67[j&3];
  union { bfrag_t v; unsigned u[4]; } pk;
  #pragma unroll
  for (int k = 0; k < 4; ++k) pk.u[k] = pack2(hA*low[2*k], hA*low[2*k+1]);
  *(bfrag_t*)(Ab + ag2*1024 + am*16) = pk.v;
  #pragma unroll
  for (int k = 0; k < 4; ++k) pk.u[k] = pack2(hB*low[2*k], hB*low[2*k+1]);
  *(bfrag_t*)(Ab + ag2*1024 + 512 + am*16) = pk.v;
}

// ---------------------------------------------------------------------------
// qgemm R13 (unchanged): 512 thr = 8 waves, grid 256, 4 iters of 128 rows.
// Per iter: S1 x4 subs (swapped MFMA, ex bit-sign partials -> exw) | B2 |
// deferred out(prev) + exw->exf reduce WITH bf16 pack + A-build x4(next) |
// B3 | S2 x4 (1 MFMA each vs resident w3-frag; fa = 1 b128 read) + qp.
// 2 barriers/iter (8 total). LDS 111KB.
// ---------------------------------------------------------------------------
__global__ __launch_bounds__(512, 2)
void qgemm(const float* __restrict__ enc,
           const unsigned short* __restrict__ Bm, const unsigned short* __restrict__ Gm,
           const float* __restrict__ b3a, const float* __restrict__ w4a, const float* __restrict__ b4a,
           const float* __restrict__ b3b, const float* __restrict__ w4b, const float* __restrict__ b4b,
           float* __restrict__ out, int Bn) {
  __shared__ __align__(16) char APq[111104];
  char* Abase = APq;                       // [sub*16384 + g2*1024 + half*512 + m*16]
  float* exw = (float*)(APq + 65536);      // [sub*2304 + w*288 + m*9 + q] f32
  unsigned* exf = (unsigned*)(APq + 102400); // [sub*256 + m*8 + k2] u32 (bf16 pair)
  float* qp  = (float*)(APq + 106496);     // [row*9 + w] f32 (128x9)

  int tid = threadIdx.x;
  int lane = tid & 63;
  int w = tid >> 6;
  int il = lane & 31;
  int h5 = lane >> 5;

  int c = blockIdx.x >> 7;
  int rowblock = blockIdx.x & 127;
  int rowsPerBlock = Bn >> 7;        // 512
  int niter = rowsPerBlock >> 7;     // 4

  // ---- persistent W-frags: tile pair (w, 8+w), 128 regs ----
  bfrag_t bf0[16], bf1[16];
  {
    const unsigned short* base = Bm + ((size_t)(c*512 + 32*w + il)*256 + h5*8);
    #pragma unroll
    for (int ks = 0; ks < 16; ++ks) {
      bf0[ks] = *(const bfrag_t*)(base + ks*16);
      bf1[ks] = *(const bfrag_t*)(base + 256*256 + ks*16);
    }
  }
  // resident w3s/b3s A-frag (4 VGPRs)
  bfrag_t gf2 = *(const bfrag_t*)(Gm + ((size_t)((c*8 + w)*64 + lane))*8);

  int n2 = 32*w + il;
  const float* w4c = c ? w4b : w4a;
  const float* b4c = c ? b4b : b4a;
  float w4v = w4c[n2];
  float b4v = b4c[0];
  // sign mask for the wave's 32-col w4 slice (bits = il, duplicated 32-63)
  unsigned smask = (unsigned)__ballot(w4v < 0.f);

  int am = tid & 31, ag2 = tid >> 5;
  const float* encb = enc + ((size_t)c*Bn)*8;
  int rbase = rowblock*rowsPerBlock;

  // ---- prologue: A-build for first 128 rows ----
  #pragma unroll
  for (int sub = 0; sub < 4; ++sub) {
    const float* ep = encb + (size_t)(rbase + sub*32 + am)*8;
    float4 pa = *(const float4*)ep, pb = *(const float4*)(ep + 4);
    a_build(pa, pb, Abase + sub*16384, ag2, am);
  }
  __syncthreads();

  for (int st = 0; st < niter; ++st) {
    int r0 = rbase + st*128;
    // ===== phase1: stage1 x4 subs, swapped operands; ex partials =====
    #pragma unroll
    for (int sub = 0; sub < 4; ++sub) {
      const char* Asel = Abase + sub*16384;
      accv_t acc0 = {}, acc1 = {};
      #pragma unroll
      for (int ks = 0; ks < 16; ++ks) {
        bfrag_t af = *(const bfrag_t*)(Asel + ks*1024 + lane*16);
        acc0 = __builtin_amdgcn_mfma_f32_32x32x16_bf16(bf0[ks], af, acc0, 0, 0, 0);
        acc1 = __builtin_amdgcn_mfma_f32_32x32x16_bf16(bf1[ks], af, acc1, 0, 0, 0);
      }
      // lane holds P[i_local(r,h5)][m=il]; i bits: 0-1=r&3, 2=h5, 3-4=r>>2
      float Pv[16];
      #pragma unroll
      for (int r = 0; r < 16; ++r) Pv[r] = acc0[r]*acc0[r] + acc1[r]*acc1[r];
      float E  = ((Pv[0]+Pv[1])+(Pv[2]+Pv[3])) + ((Pv[4]+Pv[5])+(Pv[6]+Pv[7]));
      float S4 = ((Pv[8]+Pv[9])+(Pv[10]+Pv[11])) + ((Pv[12]+Pv[13])+(Pv[14]+Pv[15]));
      float T  = E + S4;
      float S0 = ((Pv[1]+Pv[3])+(Pv[5]+Pv[7])) + ((Pv[9]+Pv[11])+(Pv[13]+Pv[15]));
      float S1 = ((Pv[2]+Pv[3])+(Pv[6]+Pv[7])) + ((Pv[10]+Pv[11])+(Pv[14]+Pv[15]));
      float S3 = ((Pv[4]+Pv[5])+(Pv[6]+Pv[7])) + ((Pv[12]+Pv[13])+(Pv[14]+Pv[15]));
      float e[8];
      e[7] = T - 2.f*S0;           // q=7 <- i bit0
      e[6] = T - 2.f*S1;           // bit1
      e[5] = h5 ? -T : T;          // bit2 = h5
      e[4] = T - 2.f*S3;           // bit3
      e[3] = T - 2.f*S4;           // bit4
      e[2] = (w&1) ? -T : T;       // bit5
      e[1] = (w&2) ? -T : T;       // bit6
      e[0] = (w&4) ? -T : T;       // bit7
      #pragma unroll
      for (int q = 0; q < 8; ++q) e[q] += __shfl_xor(e[q], 32);
      if (h5 == 0) {
        float* dst = exw + sub*2304 + w*288 + il*9;
        #pragma unroll
        for (int q = 0; q < 8; ++q) dst[q] = e[q];
      }
    }
    __syncthreads();                                   // B2: exw ready, A reads done
    // ===== phase2: deferred out(prev) + exw->exf(bf16-packed) + A-build =====
    if (st > 0 && tid < 128) {
      const float* qr = qp + tid*9;
      float s = ((qr[0]+qr[1]) + (qr[2]+qr[3])) + ((qr[4]+qr[5]) + (qr[6]+qr[7]));
      out[(size_t)c*Bn + (r0 - 128) + tid] = s + b4v;
    }
    {
      // thread -> (sub = t>>7, m = (t>>2)&31, k2 = t&3): two q sums + pack
      int sub = tid >> 7, m = (tid >> 2) & 31, k2 = tid & 3;
      const float* ew0 = exw + sub*2304 + m*9 + 2*k2;
      float s0 = ((ew0[0] + ew0[288]) + (ew0[2*288] + ew0[3*288]))
               + ((ew0[4*288] + ew0[5*288]) + (ew0[6*288] + ew0[7*288]));
      const float* ew1 = ew0 + 1;
      float s1 = ((ew1[0] + ew1[288]) + (ew1[2*288] + ew1[3*288]))
               + ((ew1[4*288] + ew1[5*288]) + (ew1[6*288] + ew1[7*288]));
      exf[sub*256 + m*8 + k2] = pack2(s0, s1);
    }
    bool more = (st + 1 < niter);
    if (more) {
      #pragma unroll
      for (int sub = 0; sub < 4; ++sub) {
        const float* ep = encb + (size_t)(r0 + 128 + sub*32 + am)*8;
        float4 pa = *(const float4*)ep, pb = *(const float4*)(ep + 4);
        a_build(pa, pb, Abase + sub*16384, ag2, am);
      }
    }
    __syncthreads();                                   // B3: exf + next-A ready
    // ===== phase3: stage2 x4 (lane=m, r=n; bias in k=8 row) + qp =====
    #pragma unroll
    for (int sub = 0; sub < 4; ++sub) {
      union { bfrag_t v; unsigned u[4]; } fa;
      if (h5 == 0) {
        fa.v = *(const bfrag_t*)(exf + sub*256 + il*8);
      } else {
        // k=8 bias row: constant 1.0 multiplies Gm2's b3s row
        fa.u[0] = 0x00003F80u; fa.u[1]=0; fa.u[2]=0; fa.u[3]=0;
      }
      accv_t acc2 = {};
      acc2 = __builtin_amdgcn_mfma_f32_32x32x16_bf16(gf2, fa.v, acc2, 0, 0, 0);
      // lane = batch m (=il); r = n_local = (r&3)+8*(r>>2)+4*h5 in wave slice
      float qa = 0.f;
      #pragma unroll
      for (int r = 0; r < 16; ++r) {
        int bi = (r&3) + 8*(r>>2);
        float ta = fmaxf(acc2[r], 0.f);
        bool neg = ((smask >> (bi + 4*h5)) & 1u) != 0u;
        qa += neg ? -ta : ta;
      }
      qa += __shfl_xor(qa, 32);
      if (h5 == 0) qp[(sub*32 + il)*9 + w] = qa;
    }
    // no barrier: next phase1 writes exw (last read pre-B3), reads A
    // (built phase2, post-B3); qp read is after next B2.
  }
  // ---- epilogue: out-write for the last iteration ----
  __syncthreads();
  if (tid < 128) {
    const float* qr = qp + tid*9;
    float s = ((qr[0]+qr[1]) + (qr[2]+qr[3])) + ((qr[4]+qr[5]) + (qr[6]+qr[7]));
    out[(size_t)c*Bn + rbase + (niter-1)*128 + tid] = s + b4v;
  }
}

extern "C" void kernel_launch(void* const* d_in, const int* in_sizes, int n_in,
                              void* d_out, int out_size, void* d_ws, size_t ws_size,
                              hipStream_t stream) {
  (void)n_in; (void)out_size; (void)ws_size;
  const float* state  = (const float*)d_in[0];
  const float* action = (const float*)d_in[1];
  const float* w1a=(const float*)d_in[2];  const float* b1a=(const float*)d_in[3];
  const float* w2a=(const float*)d_in[4];  const float* b2a=(const float*)d_in[5];
  const float* qrxa=(const float*)d_in[6]; const float* qrya=(const float*)d_in[7];
  const float* qrza=(const float*)d_in[8];
  const float* w3a=(const float*)d_in[9];  const float* b3a=(const float*)d_in[10];
  const float* w4a=(const float*)d_in[11]; const float* b4a=(const float*)d_in[12];
  const float* w1b=(const float*)d_in[13]; const float* b1b=(const float*)d_in[14];
  const float* w2b=(const float*)d_in[15]; const float* b2b=(const float*)d_in[16];
  const float* qrxb=(const float*)d_in[17];const float* qryb=(const float*)d_in[18];
  const float* qrzb=(const float*)d_in[19];
  const float* w3b=(const float*)d_in[20]; const float* b3b=(const float*)d_in[21];
  const float* w4b=(const float*)d_in[22]; const float* b4b=(const float*)d_in[23];

  int B = in_sizes[0] / 96;
  char* wsb = (char*)d_ws;
  unsigned short* Bmat = (unsigned short*)(wsb);                 // 524288 B
  unsigned short* Gmat = (unsigned short*)(wsb + 524288);        // 16384 B used
  unsigned short* w1p  = (unsigned short*)(wsb + 786432);        // 262144 B
  unsigned short* w2p  = (unsigned short*)(wsb + 1048576);       // 65536 B
  float* enc           = (float*)(wsb + 1114112);                // 2*B*8*4 B

  prep_weights<<<232, 256, 0, stream>>>(qrxa,qrya,qrza,qrxb,qryb,qrzb,
                                        w1a,w1b,w2a,w2b,w3a,w3b,w4a,w4b,b3a,b3b,
                                        Bmat,Gmat,w1p,w2p);
  enc_mfma<<<B/64, 256, 0, stream>>>(state,action,w1p,b1a,b1b,w2p,b2a,b2b,enc,B);
  qgemm<<<256, 512, 0, stream>>>(enc, Bmat, Gmat, b3a, w4a, b4a, b3b, w4b, b4b,
                                 (float*)d_out, B);
}